// Round 1
// baseline (1268.583 us; speedup 1.0000x reference)
//
#include <hip/hip_runtime.h>

// ---------------------------------------------------------------------------
// MultiMemoryAttention on gfx950 — bf16 MFMA pipeline.
// Shapes (hardcoded): B=2, S=4096, H=2048, nh=16, hd=128, M=4, CHUNK=128, nc=32
// ---------------------------------------------------------------------------

typedef __attribute__((ext_vector_type(4))) float f32x4;
typedef __attribute__((ext_vector_type(4))) int   i32x4;
typedef __attribute__((ext_vector_type(8))) short s16x8;
typedef __attribute__((ext_vector_type(4))) float fl4;
typedef __attribute__((ext_vector_type(4))) short sh4;

__device__ __forceinline__ float bf2f(short v){
  union { unsigned int u; float f; } x; x.u = ((unsigned int)(unsigned short)v) << 16; return x.f;
}
__device__ __forceinline__ short f2bf(float f){
  union { float f; unsigned int u; } x; x.f = f;
  unsigned int r = x.u + 0x7fffu + ((x.u >> 16) & 1u);
  return (short)(r >> 16);
}
__device__ __forceinline__ float seplus(float x){ return x > 0.f ? x + 1.f : __expf(x); }

// 16x16x32 bf16 MFMA via inline asm (avoids builtin signature drift; operands
// are 4-VGPR tuples; C==D accumulate in place).
__device__ __forceinline__ void mfma_bf16(f32x4& d, i32x4 a, i32x4 b){
  asm("v_mfma_f32_16x16x32_bf16 %0, %1, %2, %0" : "+v"(d) : "v"(a), "v"(b));
}

// async global->LDS, 16B per lane; lds dest must be wave-uniform base.
__device__ __forceinline__ void gload_lds16(const void* g, void* l){
  __builtin_amdgcn_global_load_lds((__attribute__((address_space(1))) unsigned int*)(g),
                                   (__attribute__((address_space(3))) unsigned int*)(l), 16, 0, 0);
}

// C[row_of_A][row_of_B] += sum_k A[ra][k]*B[rb][k]  over K = 32*NKK, tiles
// row-major with leading dim LDK (elements). Wave (wm,wn) owns a 64x64 tile.
template<int LDK, int NKK>
__device__ __forceinline__ void mm_tile(const short* Ab, const short* Bb,
                                        f32x4 (&acc)[4][4], int lane, int wm, int wn){
  const int r = lane & 15, ks8 = (lane >> 4) * 8;
  #pragma unroll
  for (int kk = 0; kk < NKK; ++kk){
    i32x4 a[4], b[4];
    #pragma unroll
    for (int mi = 0; mi < 4; ++mi)
      a[mi] = *(const i32x4*)(Ab + (wm*64 + mi*16 + r)*LDK + kk*32 + ks8);
    #pragma unroll
    for (int ni = 0; ni < 4; ++ni)
      b[ni] = *(const i32x4*)(Bb + (wn*64 + ni*16 + r)*LDK + kk*32 + ks8);
    #pragma unroll
    for (int mi = 0; mi < 4; ++mi)
      #pragma unroll
      for (int ni = 0; ni < 4; ++ni)
        mfma_bf16(acc[mi][ni], a[mi], b[ni]);
  }
}

#define ZERO44(A) do { _Pragma("unroll") for (int _i=0;_i<4;++_i){ _Pragma("unroll") for (int _j=0;_j<4;++_j){ A[_i][_j][0]=0.f;A[_i][_j][1]=0.f;A[_i][_j][2]=0.f;A[_i][_j][3]=0.f; } } } while(0)

// ---------------------------------------------------------------------------
// fp32 -> bf16 convert, float4-vectorized
__global__ __launch_bounds__(256) void k_f2b4(const float* __restrict__ s,
                                              short* __restrict__ d, int n4){
  int i = blockIdx.x*256 + threadIdx.x, st = gridDim.x*256;
  for (; i < n4; i += st){
    fl4 v = ((const fl4*)s)[i];
    sh4 o;
    #pragma unroll
    for (int j = 0; j < 4; ++j) o[j] = f2bf(v[j]);
    ((sh4*)d)[i] = o;
  }
}

// memories [M,nh,hd,hd] fp32 -> memT [M*nh][e][d] bf16 (transposed)
__global__ __launch_bounds__(256) void k_memT(const float* __restrict__ mem,
                                              short* __restrict__ memT){
  const int mh = blockIdx.x;
  const float* s = mem + (size_t)mh*16384;
  short* d = memT + (size_t)mh*16384;
  for (int i = threadIdx.x; i < 16384; i += 256){
    int dd = i >> 7, e = i & 127;
    d[e*128 + dd] = f2bf(s[i]);
  }
}

// ---------------------------------------------------------------------------
// GEMM: C[8192,2048] = A[8192,2048] @ B[2048,2048]^T, A,B bf16 row-major.
// mode 0: bf16 out to [B,nh,S,hd]; mode 1: fp32 out row-major [m][n].
__global__ __launch_bounds__(256) void k_gemm(const short* __restrict__ A,
                                              const short* __restrict__ B,
                                              void* __restrict__ outp, int mode){
  __shared__ short As[128*64];
  __shared__ short Bs[128*64];
  const int tid = threadIdx.x, lane = tid & 63, wv = tid >> 6;
  const int wm = wv >> 1, wn = wv & 1;
  const int bm = blockIdx.x, bn = blockIdx.y;
  const size_t aBase = (size_t)bm * 128 * 2048;
  const size_t bBase = (size_t)bn * 128 * 2048;
  f32x4 acc[4][4]; ZERO44(acc);

  for (int kb = 0; kb < 2048; kb += 64){
    #pragma unroll
    for (int i = 0; i < 4; ++i){
      const int off = i*4096 + tid*16;          // byte offset in 16KB tile
      const int row = off >> 7;                  // 128 B per row (64 bf16)
      const int cole = (off & 127) >> 1;         // element col
      gload_lds16(A + aBase + (size_t)row*2048 + kb + cole, (char*)As + i*4096 + wv*1024);
      gload_lds16(B + bBase + (size_t)row*2048 + kb + cole, (char*)Bs + i*4096 + wv*1024);
    }
    __syncthreads();
    mm_tile<64,2>(As, Bs, acc, lane, wm, wn);
    __syncthreads();
  }

  const int rq = (lane >> 4) * 4, cn = lane & 15;
  if (mode == 0){
    short* o = (short*)outp;
    #pragma unroll
    for (int mi = 0; mi < 4; ++mi)
      #pragma unroll
      for (int ni = 0; ni < 4; ++ni)
        #pragma unroll
        for (int i = 0; i < 4; ++i){
          int mrow = bm*128 + wm*64 + mi*16 + rq + i;
          int ncol = bn*128 + wn*64 + ni*16 + cn;
          int b = mrow >> 12, s = mrow & 4095, h = ncol >> 7, dd = ncol & 127;
          o[((size_t)(b*16 + h)*4096 + s)*128 + dd] = f2bf(acc[mi][ni][i]);
        }
  } else {
    float* o = (float*)outp;
    #pragma unroll
    for (int mi = 0; mi < 4; ++mi)
      #pragma unroll
      for (int ni = 0; ni < 4; ++ni)
        #pragma unroll
        for (int i = 0; i < 4; ++i){
          int mrow = bm*128 + wm*64 + mi*16 + rq + i;
          int ncol = bn*128 + wn*64 + ni*16 + cn;
          o[(size_t)mrow*2048 + ncol] = acc[mi][ni][i];
        }
  }
}

// ---------------------------------------------------------------------------
// rel + softmax over memories: w[m,b,h]. One block per (b,h).
__global__ __launch_bounds__(256) void k_rel(const short* __restrict__ qb,
                                             const float* __restrict__ lm,
                                             const float* __restrict__ kc,
                                             float* __restrict__ wsm){
  const int bh = blockIdx.x, b = bh >> 4, h = bh & 15, t = threadIdx.x;
  __shared__ float tmp[256];
  __shared__ float qs[128];
  __shared__ float relv[4];
  const short* qrow = qb + (size_t)bh*4096*128;
  float acc = 0.f;
  const int d = t & 127, p = t >> 7;
  for (int s = p; s < 4096; s += 2) acc += bf2f(qrow[(size_t)s*128 + d]);
  tmp[t] = acc; __syncthreads();
  if (t < 128) qs[t] = tmp[t] + tmp[t+128];
  __syncthreads();
  for (int m = 0; m < 4; ++m){
    float v = (t < 128) ? qs[t]*lm[(m*16 + h)*128 + t] : 0.f;
    tmp[t] = v; __syncthreads();
    for (int o = 128; o > 0; o >>= 1){ if (t < o) tmp[t] += tmp[t+o]; __syncthreads(); }
    if (t == 0) relv[m] = tmp[0] * (1.f/4096.f);
    __syncthreads();
  }
  if (t == 0){
    float w[4]; float mx = -1e30f;
    for (int m = 0; m < 4; ++m){
      float s = 0.f;
      for (int hh = 0; hh < 16; ++hh) s += kc[m*16 + hh];
      w[m] = (s >= 1e-6f) ? relv[m] : -1e30f;
      mx = fmaxf(mx, w[m]);
    }
    float den = 0.f;
    for (int m = 0; m < 4; ++m){ w[m] = __expf(w[m] - mx); den += w[m]; }
    for (int m = 0; m < 4; ++m) wsm[(m*2 + b)*16 + h] = w[m] / den;
  }
}

// ---------------------------------------------------------------------------
// Pass A: per-chunk Sc^T[e][d] = sum_k v[k][e]*sk[k][d] (bf16) and zc[d].
__global__ __launch_bounds__(256) void k_passA(const short* __restrict__ kin,
                                               const short* __restrict__ vin,
                                               short* __restrict__ Sc,
                                               float* __restrict__ zc){
  __shared__ short skT[128*128];
  __shared__ short vT[128*128];
  const int bid = blockIdx.x;                 // bh*32 + c
  const int tid = threadIdx.x, lane = tid & 63, wv = tid >> 6;
  const int wm = wv >> 1, wn = wv & 1;
  const size_t rb = (size_t)bid * 16384;
  const short* kp = kin + rb;
  const short* vp = vin + rb;
  const int kl = tid >> 1, dh = (tid & 1) * 64;
  #pragma unroll
  for (int j = 0; j < 8; ++j){
    s16x8 pk = *(const s16x8*)(kp + kl*128 + dh + j*8);
    s16x8 pv = *(const s16x8*)(vp + kl*128 + dh + j*8);
    #pragma unroll
    for (int e = 0; e < 8; ++e){
      int dd = dh + j*8 + e;
      skT[dd*128 + kl] = f2bf(seplus(bf2f(pk[e])));
      vT [dd*128 + kl] = pv[e];
    }
  }
  __syncthreads();
  if (tid < 128){
    float z = 0.f;
    for (int k2 = 0; k2 < 128; ++k2) z += bf2f(skT[tid*128 + k2]);
    zc[(size_t)bid*128 + tid] = z;
  }
  f32x4 acc[4][4]; ZERO44(acc);
  mm_tile<128,4>(vT, skT, acc, lane, wm, wn);
  short* o = Sc + rb;
  const int rq = (lane >> 4) * 4, cn = lane & 15;
  #pragma unroll
  for (int mi = 0; mi < 4; ++mi)
    #pragma unroll
    for (int ni = 0; ni < 4; ++ni)
      #pragma unroll
      for (int i = 0; i < 4; ++i){
        int e = wm*64 + mi*16 + rq + i, d = wn*64 + ni*16 + cn;
        o[e*128 + d] = f2bf(acc[mi][ni][i]);
      }
}

// Pass B: in-place exclusive prefix over chunks (per bh). S: bf16, z: fp32.
__global__ __launch_bounds__(256) void k_passB(short* __restrict__ S,
                                               float* __restrict__ z){
  const int bh = blockIdx.x, t = threadIdx.x;
  float acc[64];
  #pragma unroll
  for (int i = 0; i < 64; ++i) acc[i] = 0.f;
  float za = 0.f;
  for (int c = 0; c < 32; ++c){
    const size_t bse = ((size_t)bh*32 + c)*16384;
    #pragma unroll
    for (int i = 0; i < 64; ++i){
      size_t idx = bse + t + i*256;
      float cur = bf2f(S[idx]);
      S[idx] = f2bf(acc[i]);
      acc[i] += cur;
    }
    if (t < 128){
      size_t zi = ((size_t)bh*32 + c)*128 + t;
      float cz = z[zi]; z[zi] = za; za += cz;
    }
  }
}

// ---------------------------------------------------------------------------
// Pass M: memory retrieval, writes g*sum_m w_m*(sq@mem_m)/max(norm_m,eps).
__global__ __launch_bounds__(256) void k_passM(const short* __restrict__ qb,
    const short* __restrict__ memT, const float* __restrict__ mn,
    const float* __restrict__ wsm, const float* __restrict__ gate,
    float* __restrict__ gNM, short* __restrict__ memout){
  __shared__ short X[16384];
  __shared__ short Y[16384];
  const int bid = blockIdx.x, bh = bid >> 5, b = bh >> 4, h = bh & 15;
  const int tid = threadIdx.x, lane = tid & 63, wv = tid >> 6;
  const int wm = wv >> 1, wn = wv & 1;
  const int rq = (lane >> 4) * 4, cn = lane & 15;
  const size_t rb = (size_t)bid * 16384;
  const short* qp = qb + rb;
  for (int i = tid; i < 2048; i += 256){
    s16x8 v = *(const s16x8*)(qp + i*8);
    s16x8 o;
    #pragma unroll
    for (int e = 0; e < 8; ++e) o[e] = f2bf(seplus(bf2f(v[e])));
    *(s16x8*)(X + i*8) = o;
  }
  f32x4 macc[4][4]; ZERO44(macc);
  for (int m = 0; m < 4; ++m){
    __syncthreads();   // X ready (m=0); Y/NM reads of prior iter done
    const short* mt = memT + (size_t)(m*16 + h)*16384;
    for (int i = tid; i < 2048; i += 256)
      *(s16x8*)(Y + i*8) = *(const s16x8*)(mt + i*8);
    if (tid < 128){
      const float* mnp = mn + (m*16 + h)*128;
      float s = 0.f;
      for (int dd = 0; dd < 128; ++dd) s += bf2f(X[tid*128 + dd]) * mnp[dd];
      gNM[(size_t)bid*128 + tid] = s;
    }
    __syncthreads();
    f32x4 am[4][4]; ZERO44(am);
    mm_tile<128,4>(X, Y, am, lane, wm, wn);
    const float wmv = wsm[(m*2 + b)*16 + h];
    #pragma unroll
    for (int mi = 0; mi < 4; ++mi)
      #pragma unroll
      for (int i = 0; i < 4; ++i){
        int q = wm*64 + mi*16 + rq + i;
        float f = wmv / fmaxf(gNM[(size_t)bid*128 + q], 1e-6f);
        #pragma unroll
        for (int ni = 0; ni < 4; ++ni) macc[mi][ni][i] += f * am[mi][ni][i];
      }
  }
  const float g = 1.f / (1.f + __expf(-gate[h]));
  short* op = memout + rb;
  #pragma unroll
  for (int mi = 0; mi < 4; ++mi)
    #pragma unroll
    for (int ni = 0; ni < 4; ++ni)
      #pragma unroll
      for (int i = 0; i < 4; ++i){
        int q = wm*64 + mi*16 + rq + i, e = wn*64 + ni*16 + cn;
        op[q*128 + e] = f2bf(g * macc[mi][ni][i]);
      }
}

// ---------------------------------------------------------------------------
// Pass C: local attention per (bh,chunk) + gate-combine with memout.
__global__ __launch_bounds__(256) void k_passC(const short* __restrict__ qb,
    const short* __restrict__ kin, const short* __restrict__ vin,
    const short* __restrict__ Spref, const float* __restrict__ zpref,
    const short* __restrict__ memout, const float* __restrict__ gate,
    float* __restrict__ gNL, short* __restrict__ combined){
  __shared__ short X[16384];   // sq -> masked scores
  __shared__ short Y[16384];   // sk -> Spref^T -> v^T
  const int bid = blockIdx.x, bh = bid >> 5, c = bid & 31, b = bh >> 4, h = bh & 15;
  const int tid = threadIdx.x, lane = tid & 63, wv = tid >> 6;
  const int wm = wv >> 1, wn = wv & 1;
  const int rq = (lane >> 4) * 4, cn = lane & 15;
  const size_t rb = (size_t)bid * 16384;
  const short* qp = qb + rb;
  const short* kp = kin + rb;
  const short* vp = vin + rb;

  for (int i = tid; i < 2048; i += 256){
    s16x8 a = *(const s16x8*)(qp + i*8);
    s16x8 bb = *(const s16x8*)(kp + i*8);
    s16x8 oa, ob;
    #pragma unroll
    for (int e = 0; e < 8; ++e){ oa[e] = f2bf(seplus(bf2f(a[e]))); ob[e] = f2bf(seplus(bf2f(bb[e]))); }
    *(s16x8*)(X + i*8) = oa;
    *(s16x8*)(Y + i*8) = ob;
  }
  __syncthreads();

  f32x4 sc[4][4]; ZERO44(sc);
  mm_tile<128,4>(X, Y, sc, lane, wm, wn);        // scores[q][k]
  __syncthreads();

  for (int i = tid; i < 2048; i += 256)
    *(s16x8*)(Y + i*8) = *(const s16x8*)(Spref + rb + i*8);
  if (tid < 128){
    const float* zp = zpref + (size_t)bid*128;
    float s = 0.f;
    for (int dd = 0; dd < 128; ++dd) s += bf2f(X[tid*128 + dd]) * zp[dd];
    gNL[(size_t)bid*128 + tid] = s;
  }
  __syncthreads();

  f32x4 oacc[4][4]; ZERO44(oacc);
  mm_tile<128,4>(X, Y, oacc, lane, wm, wn);      // out1[q][e] = sq @ Spref
  __syncthreads();

  // X <- masked scores (bf16), Y <- v^T
  #pragma unroll
  for (int mi = 0; mi < 4; ++mi)
    #pragma unroll
    for (int ni = 0; ni < 4; ++ni)
      #pragma unroll
      for (int i = 0; i < 4; ++i){
        int q = wm*64 + mi*16 + rq + i, k2 = wn*64 + ni*16 + cn;
        X[q*128 + k2] = f2bf((k2 <= q) ? sc[mi][ni][i] : 0.f);
      }
  const int klv = tid >> 1, dh = (tid & 1) * 64;
  #pragma unroll
  for (int j = 0; j < 8; ++j){
    s16x8 pv = *(const s16x8*)(vp + klv*128 + dh + j*8);
    #pragma unroll
    for (int e = 0; e < 8; ++e) Y[(dh + j*8 + e)*128 + klv] = pv[e];
  }
  __syncthreads();
  if (tid < 128){
    float s = gNL[(size_t)bid*128 + tid];
    for (int k2 = 0; k2 < 128; ++k2) s += bf2f(X[tid*128 + k2]);
    gNL[(size_t)bid*128 + tid] = s;
  }
  __syncthreads();

  mm_tile<128,4>(X, Y, oacc, lane, wm, wn);      // + scoresM @ v

  const float g = 1.f / (1.f + __expf(-gate[h]));
  const float og = 1.f - g;
  const short* mo = memout + rb;
  #pragma unroll
  for (int mi = 0; mi < 4; ++mi)
    #pragma unroll
    for (int ni = 0; ni < 4; ++ni)
      #pragma unroll
      for (int i = 0; i < 4; ++i){
        int q = wm*64 + mi*16 + rq + i, e = wn*64 + ni*16 + cn;
        float nl = fmaxf(gNL[(size_t)bid*128 + q], 1e-6f);
        float outv = bf2f(mo[q*128 + e]) + og * (oacc[mi][ni][i] / nl);
        combined[((size_t)b*4096 + c*128 + q)*2048 + h*128 + e] = f2bf(outv);
      }
}

// ---------------------------------------------------------------------------
extern "C" void kernel_launch(void* const* d_in, const int* in_sizes, int n_in,
                              void* d_out, int out_size, void* d_ws, size_t ws_size,
                              hipStream_t stream){
  const float* hs   = (const float*)d_in[0];
  const float* wq   = (const float*)d_in[1];
  const float* wk   = (const float*)d_in[2];
  const float* wvp  = (const float*)d_in[3];
  const float* wo   = (const float*)d_in[4];
  const float* gate = (const float*)d_in[5];
  const float* mem  = (const float*)d_in[6];
  const float* mn   = (const float*)d_in[7];
  const float* lm   = (const float*)d_in[8];
  const float* kc   = (const float*)d_in[9];

  char* base = (char*)d_ws; size_t off = 0;
  auto alloc = [&](size_t bytes)->void*{
    void* r = base + off; off = (off + bytes + 255) & ~(size_t)255; return r;
  };
  short* hs_b  = (short*)alloc(16777216ull*2);   // reused as memout after proj
  short* wq_b  = (short*)alloc(4194304ull*2);
  short* wk_b  = (short*)alloc(4194304ull*2);
  short* wv_b  = (short*)alloc(4194304ull*2);
  short* wo_b  = (short*)alloc(4194304ull*2);
  short* q_b   = (short*)alloc(16777216ull*2);
  short* k_b   = (short*)alloc(16777216ull*2);
  short* v_b   = (short*)alloc(16777216ull*2);
  short* memT  = (short*)alloc(1048576ull*2);
  float* wsm   = (float*)alloc(128*4);
  short* SZ    = (short*)alloc(16777216ull*2);   // Sc -> Spref (in place)
  float* zz    = (float*)alloc(131072ull*4);     // zc -> zpref (in place)
  float* gNL   = (float*)alloc(131072ull*4);
  float* gNM   = (float*)alloc(131072ull*4);
  short* comb  = (short*)alloc(16777216ull*2);
  short* memout = hs_b;  // alias: hs_b dead after proj GEMMs

  k_f2b4<<<4096, 256, 0, stream>>>(hs,  hs_b, 4194304);
  k_f2b4<<<1024, 256, 0, stream>>>(wq,  wq_b, 1048576);
  k_f2b4<<<1024, 256, 0, stream>>>(wk,  wk_b, 1048576);
  k_f2b4<<<1024, 256, 0, stream>>>(wvp, wv_b, 1048576);
  k_f2b4<<<1024, 256, 0, stream>>>(wo,  wo_b, 1048576);
  k_memT<<<64, 256, 0, stream>>>(mem, memT);

  dim3 gg(64, 16);
  k_gemm<<<gg, 256, 0, stream>>>(hs_b, wq_b, q_b, 0);
  k_gemm<<<gg, 256, 0, stream>>>(hs_b, wk_b, k_b, 0);
  k_gemm<<<gg, 256, 0, stream>>>(hs_b, wv_b, v_b, 0);

  k_rel<<<32, 256, 0, stream>>>(q_b, lm, kc, wsm);
  k_passA<<<1024, 256, 0, stream>>>(k_b, v_b, SZ, zz);
  k_passB<<<32, 256, 0, stream>>>(SZ, zz);
  k_passM<<<1024, 256, 0, stream>>>(q_b, memT, mn, wsm, gate, gNM, memout);
  k_passC<<<1024, 256, 0, stream>>>(q_b, k_b, v_b, SZ, zz, memout, gate, gNL, comb);

  k_gemm<<<gg, 256, 0, stream>>>(comb, wo_b, d_out, 1);
}

// Round 2
// 713.350 us; speedup vs baseline: 1.7783x; 1.7783x over previous
//
#include <hip/hip_runtime.h>

// ---------------------------------------------------------------------------
// MultiMemoryAttention on gfx950 — bf16 MFMA pipeline.
// Shapes (hardcoded): B=2, S=4096, H=2048, nh=16, hd=128, M=4, CHUNK=128, nc=32
// ---------------------------------------------------------------------------

typedef __attribute__((ext_vector_type(4))) float f32x4;
typedef __attribute__((ext_vector_type(4))) int   i32x4;
typedef __attribute__((ext_vector_type(8))) short s16x8;
typedef __attribute__((ext_vector_type(4))) float fl4;
typedef __attribute__((ext_vector_type(4))) short sh4;

__device__ __forceinline__ float bf2f(short v){
  union { unsigned int u; float f; } x; x.u = ((unsigned int)(unsigned short)v) << 16; return x.f;
}
__device__ __forceinline__ short f2bf(float f){
  union { float f; unsigned int u; } x; x.f = f;
  unsigned int r = x.u + 0x7fffu + ((x.u >> 16) & 1u);
  return (short)(r >> 16);
}
__device__ __forceinline__ float seplus(float x){ return x > 0.f ? x + 1.f : __expf(x); }

__device__ __forceinline__ void mfma_bf16(f32x4& d, i32x4 a, i32x4 b){
  asm("v_mfma_f32_16x16x32_bf16 %0, %1, %2, %0" : "+v"(d) : "v"(a), "v"(b));
}

__device__ __forceinline__ void gload_lds16(const void* g, void* l){
  __builtin_amdgcn_global_load_lds((__attribute__((address_space(1))) unsigned int*)(g),
                                   (__attribute__((address_space(3))) unsigned int*)(l), 16, 0, 0);
}

// C[row_of_A][row_of_B] += sum_k A[ra][k]*B[rb][k]  over K = 32*NKK, tiles
// row-major with leading dim LDK (elements). Wave (wm,wn) owns a 64x64 tile.
template<int LDK, int NKK>
__device__ __forceinline__ void mm_tile(const short* Ab, const short* Bb,
                                        f32x4 (&acc)[4][4], int lane, int wm, int wn){
  const int r = lane & 15, ks8 = (lane >> 4) * 8;
  #pragma unroll
  for (int kk = 0; kk < NKK; ++kk){
    i32x4 a[4], b[4];
    #pragma unroll
    for (int mi = 0; mi < 4; ++mi)
      a[mi] = *(const i32x4*)(Ab + (wm*64 + mi*16 + r)*LDK + kk*32 + ks8);
    #pragma unroll
    for (int ni = 0; ni < 4; ++ni)
      b[ni] = *(const i32x4*)(Bb + (wn*64 + ni*16 + r)*LDK + kk*32 + ks8);
    #pragma unroll
    for (int mi = 0; mi < 4; ++mi)
      #pragma unroll
      for (int ni = 0; ni < 4; ++ni)
        mfma_bf16(acc[mi][ni], a[mi], b[ni]);
  }
}

#define ZERO44(A) do { _Pragma("unroll") for (int _i=0;_i<4;++_i){ _Pragma("unroll") for (int _j=0;_j<4;++_j){ A[_i][_j][0]=0.f;A[_i][_j][1]=0.f;A[_i][_j][2]=0.f;A[_i][_j][3]=0.f; } } } while(0)

// ---------------------------------------------------------------------------
// fp32 -> bf16 convert, float4-vectorized
__global__ __launch_bounds__(256) void k_f2b4(const float* __restrict__ s,
                                              short* __restrict__ d, int n4){
  int i = blockIdx.x*256 + threadIdx.x, st = gridDim.x*256;
  for (; i < n4; i += st){
    fl4 v = ((const fl4*)s)[i];
    sh4 o;
    #pragma unroll
    for (int j = 0; j < 4; ++j) o[j] = f2bf(v[j]);
    ((sh4*)d)[i] = o;
  }
}

// memories [M,nh,hd,hd] fp32 -> memT [M*nh][e][d] bf16 (transposed)
__global__ __launch_bounds__(256) void k_memT(const float* __restrict__ mem,
                                              short* __restrict__ memT){
  const int mh = blockIdx.x;
  const float* s = mem + (size_t)mh*16384;
  short* d = memT + (size_t)mh*16384;
  for (int i = threadIdx.x; i < 16384; i += 256){
    int dd = i >> 7, e = i & 127;
    d[e*128 + dd] = f2bf(s[i]);
  }
}

// ---------------------------------------------------------------------------
// GEMM: C[8192,2048] = A[8192,2048] @ B[2048,2048]^T, A,B bf16 row-major.
// mode 0: bf16 out to [B,nh,S,hd]; mode 1: fp32 out row-major [m][n].
__global__ __launch_bounds__(256) void k_gemm(const short* __restrict__ A,
                                              const short* __restrict__ B,
                                              void* __restrict__ outp, int mode){
  __shared__ short As[128*64];
  __shared__ short Bs[128*64];
  const int tid = threadIdx.x, lane = tid & 63, wv = tid >> 6;
  const int wm = wv >> 1, wn = wv & 1;
  const int bm = blockIdx.x, bn = blockIdx.y;
  const size_t aBase = (size_t)bm * 128 * 2048;
  const size_t bBase = (size_t)bn * 128 * 2048;
  f32x4 acc[4][4]; ZERO44(acc);

  for (int kb = 0; kb < 2048; kb += 64){
    #pragma unroll
    for (int i = 0; i < 4; ++i){
      const int off = i*4096 + tid*16;          // byte offset in 16KB tile
      const int row = off >> 7;                  // 128 B per row (64 bf16)
      const int cole = (off & 127) >> 1;         // element col
      gload_lds16(A + aBase + (size_t)row*2048 + kb + cole, (char*)As + i*4096 + wv*1024);
      gload_lds16(B + bBase + (size_t)row*2048 + kb + cole, (char*)Bs + i*4096 + wv*1024);
    }
    __syncthreads();
    mm_tile<64,2>(As, Bs, acc, lane, wm, wn);
    __syncthreads();
  }

  const int rq = (lane >> 4) * 4, cn = lane & 15;
  if (mode == 0){
    short* o = (short*)outp;
    #pragma unroll
    for (int mi = 0; mi < 4; ++mi)
      #pragma unroll
      for (int ni = 0; ni < 4; ++ni)
        #pragma unroll
        for (int i = 0; i < 4; ++i){
          int mrow = bm*128 + wm*64 + mi*16 + rq + i;
          int ncol = bn*128 + wn*64 + ni*16 + cn;
          int b = mrow >> 12, s = mrow & 4095, h = ncol >> 7, dd = ncol & 127;
          o[((size_t)(b*16 + h)*4096 + s)*128 + dd] = f2bf(acc[mi][ni][i]);
        }
  } else {
    float* o = (float*)outp;
    #pragma unroll
    for (int mi = 0; mi < 4; ++mi)
      #pragma unroll
      for (int ni = 0; ni < 4; ++ni)
        #pragma unroll
        for (int i = 0; i < 4; ++i){
          int mrow = bm*128 + wm*64 + mi*16 + rq + i;
          int ncol = bn*128 + wn*64 + ni*16 + cn;
          o[(size_t)mrow*2048 + ncol] = acc[mi][ni][i];
        }
  }
}

// ---------------------------------------------------------------------------
// qsum pass: partial[bh*16+sl][d] = sum over 256 rows of q (vectorized).
__global__ __launch_bounds__(256) void k_qsum(const short* __restrict__ qb,
                                              float* __restrict__ partial){
  const int bid = blockIdx.x, bh = bid >> 4, sl = bid & 15;
  const int t = threadIdx.x, dvec = t & 15, rg = t >> 4;
  const short* qp = qb + (size_t)bh*4096*128 + (size_t)sl*256*128;
  float acc[8];
  #pragma unroll
  for (int e = 0; e < 8; ++e) acc[e] = 0.f;
  for (int r = 0; r < 16; ++r){
    s16x8 v = *(const s16x8*)(qp + (rg*16 + r)*128 + dvec*8);
    #pragma unroll
    for (int e = 0; e < 8; ++e) acc[e] += bf2f(v[e]);
  }
  __shared__ float red[16][128];
  #pragma unroll
  for (int e = 0; e < 8; ++e) red[rg][dvec*8 + e] = acc[e];
  __syncthreads();
  if (t < 128){
    float s = 0.f;
    #pragma unroll
    for (int r = 0; r < 16; ++r) s += red[r][t];
    partial[(size_t)bid*128 + t] = s;
  }
}

// rel + softmax over memories from qsum partials. One block per (b,h).
__global__ __launch_bounds__(128) void k_relw(const float* __restrict__ partial,
                                              const float* __restrict__ lm,
                                              const float* __restrict__ kc,
                                              float* __restrict__ wsm){
  const int bh = blockIdx.x, b = bh >> 4, h = bh & 15, t = threadIdx.x;
  __shared__ float tmp[128];
  __shared__ float relv[4];
  float qs = 0.f;
  #pragma unroll
  for (int sl = 0; sl < 16; ++sl) qs += partial[((size_t)bh*16 + sl)*128 + t];
  for (int m = 0; m < 4; ++m){
    tmp[t] = qs * lm[(m*16 + h)*128 + t];
    __syncthreads();
    for (int o = 64; o > 0; o >>= 1){ if (t < o) tmp[t] += tmp[t+o]; __syncthreads(); }
    if (t == 0) relv[m] = tmp[0] * (1.f/4096.f);
    __syncthreads();
  }
  if (t == 0){
    float w[4]; float mx = -1e30f;
    for (int m = 0; m < 4; ++m){
      float s = 0.f;
      for (int hh = 0; hh < 16; ++hh) s += kc[m*16 + hh];
      w[m] = (s >= 1e-6f) ? relv[m] : -1e30f;
      mx = fmaxf(mx, w[m]);
    }
    float den = 0.f;
    for (int m = 0; m < 4; ++m){ w[m] = __expf(w[m] - mx); den += w[m]; }
    for (int m = 0; m < 4; ++m) wsm[(m*2 + b)*16 + h] = w[m] / den;
  }
}

// ---------------------------------------------------------------------------
// Pass A: per-chunk Sc^T[e][d] = sum_k v[k][e]*sk[k][d] (bf16) and zc[d].
__global__ __launch_bounds__(256) void k_passA(const short* __restrict__ kin,
                                               const short* __restrict__ vin,
                                               short* __restrict__ Sc,
                                               float* __restrict__ zc){
  __shared__ short skT[128*128];
  __shared__ short vT[128*128];
  const int bid = blockIdx.x;                 // bh*32 + c
  const int tid = threadIdx.x, lane = tid & 63, wv = tid >> 6;
  const int wm = wv >> 1, wn = wv & 1;
  const size_t rb = (size_t)bid * 16384;
  const short* kp = kin + rb;
  const short* vp = vin + rb;
  const int kl = tid >> 1, dh = (tid & 1) * 64;
  #pragma unroll
  for (int j = 0; j < 8; ++j){
    s16x8 pk = *(const s16x8*)(kp + kl*128 + dh + j*8);
    s16x8 pv = *(const s16x8*)(vp + kl*128 + dh + j*8);
    #pragma unroll
    for (int e = 0; e < 8; ++e){
      int dd = dh + j*8 + e;
      skT[dd*128 + kl] = f2bf(seplus(bf2f(pk[e])));
      vT [dd*128 + kl] = pv[e];
    }
  }
  __syncthreads();
  if (tid < 128){
    float z = 0.f;
    for (int k2 = 0; k2 < 128; ++k2) z += bf2f(skT[tid*128 + k2]);
    zc[(size_t)bid*128 + tid] = z;
  }
  f32x4 acc[4][4]; ZERO44(acc);
  mm_tile<128,4>(vT, skT, acc, lane, wm, wn);
  short* o = Sc + rb;
  const int rq = (lane >> 4) * 4, cn = lane & 15;
  #pragma unroll
  for (int mi = 0; mi < 4; ++mi)
    #pragma unroll
    for (int ni = 0; ni < 4; ++ni)
      #pragma unroll
      for (int i = 0; i < 4; ++i){
        int e = wm*64 + mi*16 + rq + i, d = wn*64 + ni*16 + cn;
        o[e*128 + d] = f2bf(acc[mi][ni][i]);
      }
}

// Pass B (parallel): exclusive prefix over 32 chunks, one thread per element.
__global__ __launch_bounds__(256) void k_scanS(short* __restrict__ S){
  const int gid = blockIdx.x*256 + threadIdx.x;       // < 524288
  const int bh = gid >> 14, elem = gid & 16383;
  short* p = S + (size_t)bh*32*16384 + elem;
  float a[32];
  #pragma unroll
  for (int c = 0; c < 32; ++c) a[c] = bf2f(p[(size_t)c*16384]);
  float run = 0.f;
  #pragma unroll
  for (int c = 0; c < 32; ++c){ float cur = a[c]; p[(size_t)c*16384] = f2bf(run); run += cur; }
}

__global__ __launch_bounds__(256) void k_scanZ(float* __restrict__ z){
  const int gid = blockIdx.x*256 + threadIdx.x;       // < 4096
  const int bh = gid >> 7, d = gid & 127;
  float* p = z + (size_t)bh*32*128 + d;
  float a[32];
  #pragma unroll
  for (int c = 0; c < 32; ++c) a[c] = p[c*128];
  float run = 0.f;
  #pragma unroll
  for (int c = 0; c < 32; ++c){ float cur = a[c]; p[c*128] = run; run += cur; }
}

// ---------------------------------------------------------------------------
// Pass M: memory retrieval, writes g*sum_m w_m*(sq@mem_m)/max(norm_m,eps).
__global__ __launch_bounds__(256) void k_passM(const short* __restrict__ qb,
    const short* __restrict__ memT, const float* __restrict__ mn,
    const float* __restrict__ wsm, const float* __restrict__ gate,
    float* __restrict__ gNM, short* __restrict__ memout){
  __shared__ short X[16384];
  __shared__ short Y[16384];
  const int bid = blockIdx.x, bh = bid >> 5, b = bh >> 4, h = bh & 15;
  const int tid = threadIdx.x, lane = tid & 63, wv = tid >> 6;
  const int wm = wv >> 1, wn = wv & 1;
  const int rq = (lane >> 4) * 4, cn = lane & 15;
  const size_t rb = (size_t)bid * 16384;
  const short* qp = qb + rb;
  for (int i = tid; i < 2048; i += 256){
    s16x8 v = *(const s16x8*)(qp + i*8);
    s16x8 o;
    #pragma unroll
    for (int e = 0; e < 8; ++e) o[e] = f2bf(seplus(bf2f(v[e])));
    *(s16x8*)(X + i*8) = o;
  }
  f32x4 macc[4][4]; ZERO44(macc);
  for (int m = 0; m < 4; ++m){
    __syncthreads();   // X ready (m=0); Y/NM reads of prior iter done
    const short* mt = memT + (size_t)(m*16 + h)*16384;
    for (int i = tid; i < 2048; i += 256)
      *(s16x8*)(Y + i*8) = *(const s16x8*)(mt + i*8);
    if (tid < 128){
      const float* mnp = mn + (m*16 + h)*128;
      float s = 0.f;
      for (int dd = 0; dd < 128; ++dd) s += bf2f(X[tid*128 + dd]) * mnp[dd];
      gNM[(size_t)bid*128 + tid] = s;
    }
    __syncthreads();
    f32x4 am[4][4]; ZERO44(am);
    mm_tile<128,4>(X, Y, am, lane, wm, wn);
    const float wmv = wsm[(m*2 + b)*16 + h];
    #pragma unroll
    for (int mi = 0; mi < 4; ++mi)
      #pragma unroll
      for (int i = 0; i < 4; ++i){
        int q = wm*64 + mi*16 + rq + i;
        float f = wmv / fmaxf(gNM[(size_t)bid*128 + q], 1e-6f);
        #pragma unroll
        for (int ni = 0; ni < 4; ++ni) macc[mi][ni][i] += f * am[mi][ni][i];
      }
  }
  const float g = 1.f / (1.f + __expf(-gate[h]));
  short* op = memout + rb;
  #pragma unroll
  for (int mi = 0; mi < 4; ++mi)
    #pragma unroll
    for (int ni = 0; ni < 4; ++ni)
      #pragma unroll
      for (int i = 0; i < 4; ++i){
        int q = wm*64 + mi*16 + rq + i, e = wn*64 + ni*16 + cn;
        op[q*128 + e] = f2bf(g * macc[mi][ni][i]);
      }
}

// ---------------------------------------------------------------------------
// Pass C: local attention per (bh,chunk) + gate-combine with memout.
__global__ __launch_bounds__(256) void k_passC(const short* __restrict__ qb,
    const short* __restrict__ kin, const short* __restrict__ vin,
    const short* __restrict__ Spref, const float* __restrict__ zpref,
    const short* __restrict__ memout, const float* __restrict__ gate,
    float* __restrict__ gNL, short* __restrict__ combined){
  __shared__ short X[16384];   // sq -> masked scores
  __shared__ short Y[16384];   // sk -> Spref^T -> v^T
  const int bid = blockIdx.x, bh = bid >> 5, c = bid & 31, b = bh >> 4, h = bh & 15;
  const int tid = threadIdx.x, lane = tid & 63, wv = tid >> 6;
  const int wm = wv >> 1, wn = wv & 1;
  const int rq = (lane >> 4) * 4, cn = lane & 15;
  const size_t rb = (size_t)bid * 16384;
  const short* qp = qb + rb;
  const short* kp = kin + rb;
  const short* vp = vin + rb;

  for (int i = tid; i < 2048; i += 256){
    s16x8 a = *(const s16x8*)(qp + i*8);
    s16x8 bb = *(const s16x8*)(kp + i*8);
    s16x8 oa, ob;
    #pragma unroll
    for (int e = 0; e < 8; ++e){ oa[e] = f2bf(seplus(bf2f(a[e]))); ob[e] = f2bf(seplus(bf2f(bb[e]))); }
    *(s16x8*)(X + i*8) = oa;
    *(s16x8*)(Y + i*8) = ob;
  }
  __syncthreads();

  f32x4 sc[4][4]; ZERO44(sc);
  mm_tile<128,4>(X, Y, sc, lane, wm, wn);        // scores[q][k]
  __syncthreads();

  for (int i = tid; i < 2048; i += 256)
    *(s16x8*)(Y + i*8) = *(const s16x8*)(Spref + rb + i*8);
  if (tid < 128){
    const float* zp = zpref + (size_t)bid*128;
    float s = 0.f;
    for (int dd = 0; dd < 128; ++dd) s += bf2f(X[tid*128 + dd]) * zp[dd];
    gNL[(size_t)bid*128 + tid] = s;
  }
  __syncthreads();

  f32x4 oacc[4][4]; ZERO44(oacc);
  mm_tile<128,4>(X, Y, oacc, lane, wm, wn);      // out1[q][e] = sq @ Spref
  __syncthreads();

  // X <- masked scores (bf16), Y <- v^T
  #pragma unroll
  for (int mi = 0; mi < 4; ++mi)
    #pragma unroll
    for (int ni = 0; ni < 4; ++ni)
      #pragma unroll
      for (int i = 0; i < 4; ++i){
        int q = wm*64 + mi*16 + rq + i, k2 = wn*64 + ni*16 + cn;
        X[q*128 + k2] = f2bf((k2 <= q) ? sc[mi][ni][i] : 0.f);
      }
  const int klv = tid >> 1, dh = (tid & 1) * 64;
  #pragma unroll
  for (int j = 0; j < 8; ++j){
    s16x8 pv = *(const s16x8*)(vp + klv*128 + dh + j*8);
    #pragma unroll
    for (int e = 0; e < 8; ++e) Y[(dh + j*8 + e)*128 + klv] = pv[e];
  }
  __syncthreads();
  if (tid < 128){
    float s = gNL[(size_t)bid*128 + tid];
    for (int k2 = 0; k2 < 128; ++k2) s += bf2f(X[tid*128 + k2]);
    gNL[(size_t)bid*128 + tid] = s;
  }
  __syncthreads();

  mm_tile<128,4>(X, Y, oacc, lane, wm, wn);      // + scoresM @ v

  const float g = 1.f / (1.f + __expf(-gate[h]));
  const float og = 1.f - g;
  const short* mo = memout + rb;
  #pragma unroll
  for (int mi = 0; mi < 4; ++mi)
    #pragma unroll
    for (int ni = 0; ni < 4; ++ni)
      #pragma unroll
      for (int i = 0; i < 4; ++i){
        int q = wm*64 + mi*16 + rq + i, e = wn*64 + ni*16 + cn;
        float nl = fmaxf(gNL[(size_t)bid*128 + q], 1e-6f);
        float outv = bf2f(mo[q*128 + e]) + og * (oacc[mi][ni][i] / nl);
        combined[((size_t)b*4096 + c*128 + q)*2048 + h*128 + e] = f2bf(outv);
      }
}

// ---------------------------------------------------------------------------
extern "C" void kernel_launch(void* const* d_in, const int* in_sizes, int n_in,
                              void* d_out, int out_size, void* d_ws, size_t ws_size,
                              hipStream_t stream){
  const float* hs   = (const float*)d_in[0];
  const float* wq   = (const float*)d_in[1];
  const float* wk   = (const float*)d_in[2];
  const float* wvp  = (const float*)d_in[3];
  const float* wo   = (const float*)d_in[4];
  const float* gate = (const float*)d_in[5];
  const float* mem  = (const float*)d_in[6];
  const float* mn   = (const float*)d_in[7];
  const float* lm   = (const float*)d_in[8];
  const float* kc   = (const float*)d_in[9];

  char* base = (char*)d_ws; size_t off = 0;
  auto alloc = [&](size_t bytes)->void*{
    void* r = base + off; off = (off + bytes + 255) & ~(size_t)255; return r;
  };
  short* hs_b  = (short*)alloc(16777216ull*2);   // reused as memout after proj
  short* wq_b  = (short*)alloc(4194304ull*2);
  short* wk_b  = (short*)alloc(4194304ull*2);
  short* wv_b  = (short*)alloc(4194304ull*2);
  short* wo_b  = (short*)alloc(4194304ull*2);
  short* q_b   = (short*)alloc(16777216ull*2);
  short* k_b   = (short*)alloc(16777216ull*2);
  short* v_b   = (short*)alloc(16777216ull*2);
  short* memT  = (short*)alloc(1048576ull*2);
  float* wsm   = (float*)alloc(128*4);
  short* SZ    = (short*)alloc(16777216ull*2);   // Sc -> Spref (in place)
  float* zz    = (float*)alloc(131072ull*4);     // zc -> zpref (in place)
  float* gNL   = (float*)alloc(131072ull*4);
  float* gNM   = (float*)alloc(131072ull*4);
  short* comb  = (short*)alloc(16777216ull*2);
  float* qpart = (float*)alloc(512ull*128*4);
  short* memout = hs_b;  // alias: hs_b dead after proj GEMMs

  k_f2b4<<<4096, 256, 0, stream>>>(hs,  hs_b, 4194304);
  k_f2b4<<<1024, 256, 0, stream>>>(wq,  wq_b, 1048576);
  k_f2b4<<<1024, 256, 0, stream>>>(wk,  wk_b, 1048576);
  k_f2b4<<<1024, 256, 0, stream>>>(wvp, wv_b, 1048576);
  k_f2b4<<<1024, 256, 0, stream>>>(wo,  wo_b, 1048576);
  k_memT<<<64, 256, 0, stream>>>(mem, memT);

  dim3 gg(64, 16);
  k_gemm<<<gg, 256, 0, stream>>>(hs_b, wq_b, q_b, 0);
  k_gemm<<<gg, 256, 0, stream>>>(hs_b, wk_b, k_b, 0);
  k_gemm<<<gg, 256, 0, stream>>>(hs_b, wv_b, v_b, 0);

  k_qsum<<<512, 256, 0, stream>>>(q_b, qpart);
  k_relw<<<32, 128, 0, stream>>>(qpart, lm, kc, wsm);
  k_passA<<<1024, 256, 0, stream>>>(k_b, v_b, SZ, zz);
  k_scanS<<<2048, 256, 0, stream>>>(SZ);
  k_scanZ<<<16, 256, 0, stream>>>(zz);
  k_passM<<<1024, 256, 0, stream>>>(q_b, memT, mn, wsm, gate, gNM, memout);
  k_passC<<<1024, 256, 0, stream>>>(q_b, k_b, v_b, SZ, zz, memout, gate, gNL, comb);

  k_gemm<<<gg, 256, 0, stream>>>(comb, wo_b, d_out, 1);
}

// Round 4
// 689.202 us; speedup vs baseline: 1.8407x; 1.0350x over previous
//
#include <hip/hip_runtime.h>

// ---------------------------------------------------------------------------
// MultiMemoryAttention on gfx950 — bf16 MFMA pipeline.
// Shapes (hardcoded): B=2, S=4096, H=2048, nh=16, hd=128, M=4, CHUNK=128, nc=32
// R2: GEMM upgraded to counted-vmcnt pipelined structure (T2+T3+T4+T5):
//   128x256 tile, BK=64, 8 waves, triple-buffered LDS (144KB), per-phase
//   {ds_read | stage | barrier | lgkm | setprio+16 MFMA | barrier},
//   vmcnt(6) at tile boundaries (never 0 in steady state),
//   (row&7)<<4 XOR bank swizzle (inverse-swizzled global source), XCD swizzle.
// R3: identical resubmit (R2 bench was lost to GPU acquisition timeout).
// ---------------------------------------------------------------------------

typedef __attribute__((ext_vector_type(4))) float f32x4;
typedef __attribute__((ext_vector_type(4))) int   i32x4;
typedef __attribute__((ext_vector_type(8))) short s16x8;
typedef __attribute__((ext_vector_type(4))) float fl4;
typedef __attribute__((ext_vector_type(4))) short sh4;

__device__ __forceinline__ float bf2f(short v){
  union { unsigned int u; float f; } x; x.u = ((unsigned int)(unsigned short)v) << 16; return x.f;
}
__device__ __forceinline__ short f2bf(float f){
  union { float f; unsigned int u; } x; x.f = f;
  unsigned int r = x.u + 0x7fffu + ((x.u >> 16) & 1u);
  return (short)(r >> 16);
}
__device__ __forceinline__ float seplus(float x){ return x > 0.f ? x + 1.f : __expf(x); }

__device__ __forceinline__ void mfma_bf16(f32x4& d, i32x4 a, i32x4 b){
  asm("v_mfma_f32_16x16x32_bf16 %0, %1, %2, %0" : "+v"(d) : "v"(a), "v"(b));
}

__device__ __forceinline__ void gload_lds16(const void* g, void* l){
  __builtin_amdgcn_global_load_lds((__attribute__((address_space(1))) unsigned int*)(g),
                                   (__attribute__((address_space(3))) unsigned int*)(l), 16, 0, 0);
}

// Legacy simple tile-matmul (used by the small pass kernels; unchanged).
template<int LDK, int NKK>
__device__ __forceinline__ void mm_tile(const short* Ab, const short* Bb,
                                        f32x4 (&acc)[4][4], int lane, int wm, int wn){
  const int r = lane & 15, ks8 = (lane >> 4) * 8;
  #pragma unroll
  for (int kk = 0; kk < NKK; ++kk){
    i32x4 a[4], b[4];
    #pragma unroll
    for (int mi = 0; mi < 4; ++mi)
      a[mi] = *(const i32x4*)(Ab + (wm*64 + mi*16 + r)*LDK + kk*32 + ks8);
    #pragma unroll
    for (int ni = 0; ni < 4; ++ni)
      b[ni] = *(const i32x4*)(Bb + (wn*64 + ni*16 + r)*LDK + kk*32 + ks8);
    #pragma unroll
    for (int mi = 0; mi < 4; ++mi)
      #pragma unroll
      for (int ni = 0; ni < 4; ++ni)
        mfma_bf16(acc[mi][ni], a[mi], b[ni]);
  }
}

#define ZERO44(A) do { _Pragma("unroll") for (int _i=0;_i<4;++_i){ _Pragma("unroll") for (int _j=0;_j<4;++_j){ A[_i][_j][0]=0.f;A[_i][_j][1]=0.f;A[_i][_j][2]=0.f;A[_i][_j][3]=0.f; } } } while(0)

// ---------------------------------------------------------------------------
// fp32 -> bf16 convert, float4-vectorized
__global__ __launch_bounds__(256) void k_f2b4(const float* __restrict__ s,
                                              short* __restrict__ d, int n4){
  int i = blockIdx.x*256 + threadIdx.x, st = gridDim.x*256;
  for (; i < n4; i += st){
    fl4 v = ((const fl4*)s)[i];
    sh4 o;
    #pragma unroll
    for (int j = 0; j < 4; ++j) o[j] = f2bf(v[j]);
    ((sh4*)d)[i] = o;
  }
}

// memories [M,nh,hd,hd] fp32 -> memT [M*nh][e][d] bf16 (transposed)
__global__ __launch_bounds__(256) void k_memT(const float* __restrict__ mem,
                                              short* __restrict__ memT){
  const int mh = blockIdx.x;
  const float* s = mem + (size_t)mh*16384;
  short* d = memT + (size_t)mh*16384;
  for (int i = threadIdx.x; i < 16384; i += 256){
    int dd = i >> 7, e = i & 127;
    d[e*128 + dd] = f2bf(s[i]);
  }
}

// ---------------------------------------------------------------------------
// Pipelined GEMM: C[8192,2048] = A[8192,2048] @ B[2048,2048]^T (bf16, BT form).
// Block tile 128(M) x 256(N), BK=64, 32 K-tiles, 512 threads (8 waves 2x4),
// per-wave 64x64 output. Triple-buffered LDS ring (3 x 48KB slots).
// mode 0: bf16 out scattered to [B,nh,S,hd]; mode 1: fp32 out row-major.
__global__ __launch_bounds__(512, 2) void k_gemm2(const short* __restrict__ A,
                                                  const short* __restrict__ B,
                                                  void* __restrict__ outp, int mode){
  __shared__ short lds_[73728];                 // 3 * (8192 A + 16384 B) shorts = 144 KB
  const int tid = threadIdx.x, lane = tid & 63, w = tid >> 6;
  const int wr = w >> 2, wc = w & 3;            // 2 x 4 wave grid
  const int bid = blockIdx.x;
  const int swz = (bid & 7) * 64 + (bid >> 3);  // XCD swizzle (512 % 8 == 0, bijective)
  const int bm = swz >> 3, bn = swz & 7;        // 64 x 8 tile grid

  // ---- staging: per-thread global source (inverse-swizzled), per-wave LDS dest.
  // Round r covers LDS bytes [r*8192 + tid*16): row = r*64 + tid>>3,
  // physical col word = tid&7; logical col = ((tid&7) ^ (row&7)) * 8.
  const int srow = tid >> 3;
  const int scol = ((tid & 7) ^ (srow & 7)) << 3;
  const short* pA0 = A + ((size_t)(bm*128 +   0 + srow))*2048 + scol;
  const short* pA1 = A + ((size_t)(bm*128 +  64 + srow))*2048 + scol;
  const short* pB0 = B + ((size_t)(bn*256 +   0 + srow))*2048 + scol;
  const short* pB1 = B + ((size_t)(bn*256 +  64 + srow))*2048 + scol;
  const short* pB2 = B + ((size_t)(bn*256 + 128 + srow))*2048 + scol;
  const short* pB3 = B + ((size_t)(bn*256 + 192 + srow))*2048 + scol;
  const int ldsw = w * 1024;                    // wave-uniform byte offset in a round

  #define SLOTB(s) ((char*)lds_ + (s) * 49152)
  #define STG_A(s, kt, r, p) gload_lds16((p) + (size_t)(kt)*64, SLOTB(s) + (r)*8192 + ldsw)
  #define STG_B(s, kt, r, p) gload_lds16((p) + (size_t)(kt)*64, SLOTB(s) + 16384 + (r)*8192 + ldsw)

  // ---- ds_read fragment byte offsets (swizzled on read side) ----
  const int fr = lane & 15, fg = lane >> 4;     // frag row, k-group
  int aoff[4][2], boff[4][2];
  #pragma unroll
  for (int mi = 0; mi < 4; ++mi)
    #pragma unroll
    for (int kk = 0; kk < 2; ++kk){
      int row = wr*64 + mi*16 + fr;
      aoff[mi][kk] = ((row*128 + kk*64 + fg*16) ^ ((fr & 7) << 4));
    }
  #pragma unroll
  for (int ni = 0; ni < 4; ++ni)
    #pragma unroll
    for (int kk = 0; kk < 2; ++kk){
      int row = wc*64 + ni*16 + fr;
      boff[ni][kk] = 16384 + ((row*128 + kk*64 + fg*16) ^ ((fr & 7) << 4));
    }

  f32x4 acc[4][4]; ZERO44(acc);

  // ---- prologue: stage tiles 0 and 1 (6 loads each) ----
  STG_A(0,0,0,pA0); STG_A(0,0,1,pA1);
  STG_B(0,0,0,pB0); STG_B(0,0,1,pB1); STG_B(0,0,2,pB2); STG_B(0,0,3,pB3);
  STG_A(1,1,0,pA0); STG_A(1,1,1,pA1);
  STG_B(1,1,0,pB0); STG_B(1,1,1,pB1); STG_B(1,1,2,pB2); STG_B(1,1,3,pB3);
  asm volatile("s_waitcnt vmcnt(6)" ::: "memory");   // tile 0 resident
  __builtin_amdgcn_s_barrier();

  int slot = 0;
  #pragma unroll 1
  for (int kt = 0; kt < 32; ++kt){
    const char* sb = SLOTB(slot);
    int s2 = slot - 1; if (s2 < 0) s2 = 2;           // (slot+2)%3
    const bool st = (kt + 2) < 32;

    // ================= phase 0: quadrant ni 0-1 =================
    i32x4 ar[4][2], br01[2][2];
    #pragma unroll
    for (int mi = 0; mi < 4; ++mi){
      ar[mi][0] = *(const i32x4*)(sb + aoff[mi][0]);
      ar[mi][1] = *(const i32x4*)(sb + aoff[mi][1]);
    }
    #pragma unroll
    for (int j = 0; j < 2; ++j){
      br01[j][0] = *(const i32x4*)(sb + boff[j][0]);
      br01[j][1] = *(const i32x4*)(sb + boff[j][1]);
    }
    if (st){ STG_A(s2, kt+2, 0, pA0); STG_A(s2, kt+2, 1, pA1); STG_B(s2, kt+2, 0, pB0); }
    __builtin_amdgcn_s_barrier();
    asm volatile("s_waitcnt lgkmcnt(0)" ::: "memory");
    __builtin_amdgcn_sched_barrier(0);
    __builtin_amdgcn_s_setprio(1);
    #pragma unroll
    for (int mi = 0; mi < 4; ++mi){
      mfma_bf16(acc[mi][0], ar[mi][0], br01[0][0]);
      mfma_bf16(acc[mi][1], ar[mi][0], br01[1][0]);
      mfma_bf16(acc[mi][0], ar[mi][1], br01[0][1]);
      mfma_bf16(acc[mi][1], ar[mi][1], br01[1][1]);
    }
    __builtin_amdgcn_s_setprio(0);
    __builtin_amdgcn_s_barrier();

    // ================= phase 1: quadrant ni 2-3 =================
    i32x4 br23[2][2];
    #pragma unroll
    for (int j = 0; j < 2; ++j){
      br23[j][0] = *(const i32x4*)(sb + boff[2+j][0]);
      br23[j][1] = *(const i32x4*)(sb + boff[2+j][1]);
    }
    if (st){ STG_B(s2, kt+2, 1, pB1); STG_B(s2, kt+2, 2, pB2); STG_B(s2, kt+2, 3, pB3); }
    __builtin_amdgcn_s_barrier();
    asm volatile("s_waitcnt lgkmcnt(0)" ::: "memory");
    __builtin_amdgcn_sched_barrier(0);
    __builtin_amdgcn_s_setprio(1);
    #pragma unroll
    for (int mi = 0; mi < 4; ++mi){
      mfma_bf16(acc[mi][2], ar[mi][0], br23[0][0]);
      mfma_bf16(acc[mi][3], ar[mi][0], br23[1][0]);
      mfma_bf16(acc[mi][2], ar[mi][1], br23[0][1]);
      mfma_bf16(acc[mi][3], ar[mi][1], br23[1][1]);
    }
    __builtin_amdgcn_s_setprio(0);
    // tile boundary: counted wait — next tile's 6 loads must retire;
    // the 6 just-issued (tile kt+2) stay in flight.
    if (kt < 30)       asm volatile("s_waitcnt vmcnt(6)" ::: "memory");
    else if (kt == 30) asm volatile("s_waitcnt vmcnt(0)" ::: "memory");
    __builtin_amdgcn_s_barrier();
    slot = (slot == 2) ? 0 : slot + 1;
  }

  // ---- epilogue ----
  const int rq = fg * 4, cn = fr;
  if (mode == 0){
    short* o = (short*)outp;
    #pragma unroll
    for (int mi = 0; mi < 4; ++mi)
      #pragma unroll
      for (int ni = 0; ni < 4; ++ni)
        #pragma unroll
        for (int i = 0; i < 4; ++i){
          int mrow = bm*128 + wr*64 + mi*16 + rq + i;
          int ncol = bn*256 + wc*64 + ni*16 + cn;
          int b = mrow >> 12, s = mrow & 4095, h = ncol >> 7, dd = ncol & 127;
          o[((size_t)(b*16 + h)*4096 + s)*128 + dd] = f2bf(acc[mi][ni][i]);
        }
  } else {
    float* o = (float*)outp;
    #pragma unroll
    for (int mi = 0; mi < 4; ++mi)
      #pragma unroll
      for (int ni = 0; ni < 4; ++ni)
        #pragma unroll
        for (int i = 0; i < 4; ++i){
          int mrow = bm*128 + wr*64 + mi*16 + rq + i;
          int ncol = bn*256 + wc*64 + ni*16 + cn;
          o[(size_t)mrow*2048 + ncol] = acc[mi][ni][i];
        }
  }
  #undef SLOTB
  #undef STG_A
  #undef STG_B
}

// ---------------------------------------------------------------------------
// qsum pass: partial[bh*16+sl][d] = sum over 256 rows of q (vectorized).
__global__ __launch_bounds__(256) void k_qsum(const short* __restrict__ qb,
                                              float* __restrict__ partial){
  const int bid = blockIdx.x, bh = bid >> 4, sl = bid & 15;
  const int t = threadIdx.x, dvec = t & 15, rg = t >> 4;
  const short* qp = qb + (size_t)bh*4096*128 + (size_t)sl*256*128;
  float acc[8];
  #pragma unroll
  for (int e = 0; e < 8; ++e) acc[e] = 0.f;
  for (int r = 0; r < 16; ++r){
    s16x8 v = *(const s16x8*)(qp + (rg*16 + r)*128 + dvec*8);
    #pragma unroll
    for (int e = 0; e < 8; ++e) acc[e] += bf2f(v[e]);
  }
  __shared__ float red[16][128];
  #pragma unroll
  for (int e = 0; e < 8; ++e) red[rg][dvec*8 + e] = acc[e];
  __syncthreads();
  if (t < 128){
    float s = 0.f;
    #pragma unroll
    for (int r = 0; r < 16; ++r) s += red[r][t];
    partial[(size_t)bid*128 + t] = s;
  }
}

// rel + softmax over memories from qsum partials. One block per (b,h).
__global__ __launch_bounds__(128) void k_relw(const float* __restrict__ partial,
                                              const float* __restrict__ lm,
                                              const float* __restrict__ kc,
                                              float* __restrict__ wsm){
  const int bh = blockIdx.x, b = bh >> 4, h = bh & 15, t = threadIdx.x;
  __shared__ float tmp[128];
  __shared__ float relv[4];
  float qs = 0.f;
  #pragma unroll
  for (int sl = 0; sl < 16; ++sl) qs += partial[((size_t)bh*16 + sl)*128 + t];
  for (int m = 0; m < 4; ++m){
    tmp[t] = qs * lm[(m*16 + h)*128 + t];
    __syncthreads();
    for (int o = 64; o > 0; o >>= 1){ if (t < o) tmp[t] += tmp[t+o]; __syncthreads(); }
    if (t == 0) relv[m] = tmp[0] * (1.f/4096.f);
    __syncthreads();
  }
  if (t == 0){
    float w[4]; float mx = -1e30f;
    for (int m = 0; m < 4; ++m){
      float s = 0.f;
      for (int hh = 0; hh < 16; ++hh) s += kc[m*16 + hh];
      w[m] = (s >= 1e-6f) ? relv[m] : -1e30f;
      mx = fmaxf(mx, w[m]);
    }
    float den = 0.f;
    for (int m = 0; m < 4; ++m){ w[m] = __expf(w[m] - mx); den += w[m]; }
    for (int m = 0; m < 4; ++m) wsm[(m*2 + b)*16 + h] = w[m] / den;
  }
}

// ---------------------------------------------------------------------------
// Pass A: per-chunk Sc^T[e][d] = sum_k v[k][e]*sk[k][d] (bf16) and zc[d].
__global__ __launch_bounds__(256) void k_passA(const short* __restrict__ kin,
                                               const short* __restrict__ vin,
                                               short* __restrict__ Sc,
                                               float* __restrict__ zc){
  __shared__ short skT[128*128];
  __shared__ short vT[128*128];
  const int bid = blockIdx.x;                 // bh*32 + c
  const int tid = threadIdx.x, lane = tid & 63, wv = tid >> 6;
  const int wm = wv >> 1, wn = wv & 1;
  const size_t rb = (size_t)bid * 16384;
  const short* kp = kin + rb;
  const short* vp = vin + rb;
  const int kl = tid >> 1, dh = (tid & 1) * 64;
  #pragma unroll
  for (int j = 0; j < 8; ++j){
    s16x8 pk = *(const s16x8*)(kp + kl*128 + dh + j*8);
    s16x8 pv = *(const s16x8*)(vp + kl*128 + dh + j*8);
    #pragma unroll
    for (int e = 0; e < 8; ++e){
      int dd = dh + j*8 + e;
      skT[dd*128 + kl] = f2bf(seplus(bf2f(pk[e])));
      vT [dd*128 + kl] = pv[e];
    }
  }
  __syncthreads();
  if (tid < 128){
    float z = 0.f;
    for (int k2 = 0; k2 < 128; ++k2) z += bf2f(skT[tid*128 + k2]);
    zc[(size_t)bid*128 + tid] = z;
  }
  f32x4 acc[4][4]; ZERO44(acc);
  mm_tile<128,4>(vT, skT, acc, lane, wm, wn);
  short* o = Sc + rb;
  const int rq = (lane >> 4) * 4, cn = lane & 15;
  #pragma unroll
  for (int mi = 0; mi < 4; ++mi)
    #pragma unroll
    for (int ni = 0; ni < 4; ++ni)
      #pragma unroll
      for (int i = 0; i < 4; ++i){
        int e = wm*64 + mi*16 + rq + i, d = wn*64 + ni*16 + cn;
        o[e*128 + d] = f2bf(acc[mi][ni][i]);
      }
}

// Pass B (parallel): exclusive prefix over 32 chunks, one thread per element.
__global__ __launch_bounds__(256) void k_scanS(short* __restrict__ S){
  const int gid = blockIdx.x*256 + threadIdx.x;       // < 524288
  const int bh = gid >> 14, elem = gid & 16383;
  short* p = S + (size_t)bh*32*16384 + elem;
  float a[32];
  #pragma unroll
  for (int c = 0; c < 32; ++c) a[c] = bf2f(p[(size_t)c*16384]);
  float run = 0.f;
  #pragma unroll
  for (int c = 0; c < 32; ++c){ float cur = a[c]; p[(size_t)c*16384] = f2bf(run); run += cur; }
}

__global__ __launch_bounds__(256) void k_scanZ(float* __restrict__ z){
  const int gid = blockIdx.x*256 + threadIdx.x;       // < 4096
  const int bh = gid >> 7, d = gid & 127;
  float* p = z + (size_t)bh*32*128 + d;
  float a[32];
  #pragma unroll
  for (int c = 0; c < 32; ++c) a[c] = p[c*128];
  float run = 0.f;
  #pragma unroll
  for (int c = 0; c < 32; ++c){ float cur = a[c]; p[c*128] = run; run += cur; }
}

// ---------------------------------------------------------------------------
// Pass M: memory retrieval, writes g*sum_m w_m*(sq@mem_m)/max(norm_m,eps).
__global__ __launch_bounds__(256) void k_passM(const short* __restrict__ qb,
    const short* __restrict__ memT, const float* __restrict__ mn,
    const float* __restrict__ wsm, const float* __restrict__ gate,
    float* __restrict__ gNM, short* __restrict__ memout){
  __shared__ short X[16384];
  __shared__ short Y[16384];
  const int bid = blockIdx.x, bh = bid >> 5, b = bh >> 4, h = bh & 15;
  const int tid = threadIdx.x, lane = tid & 63, wv = tid >> 6;
  const int wm = wv >> 1, wn = wv & 1;
  const int rq = (lane >> 4) * 4, cn = lane & 15;
  const size_t rb = (size_t)bid * 16384;
  const short* qp = qb + rb;
  for (int i = tid; i < 2048; i += 256){
    s16x8 v = *(const s16x8*)(qp + i*8);
    s16x8 o;
    #pragma unroll
    for (int e = 0; e < 8; ++e) o[e] = f2bf(seplus(bf2f(v[e])));
    *(s16x8*)(X + i*8) = o;
  }
  f32x4 macc[4][4]; ZERO44(macc);
  for (int m = 0; m < 4; ++m){
    __syncthreads();   // X ready (m=0); Y/NM reads of prior iter done
    const short* mt = memT + (size_t)(m*16 + h)*16384;
    for (int i = tid; i < 2048; i += 256)
      *(s16x8*)(Y + i*8) = *(const s16x8*)(mt + i*8);
    if (tid < 128){
      const float* mnp = mn + (m*16 + h)*128;
      float s = 0.f;
      for (int dd = 0; dd < 128; ++dd) s += bf2f(X[tid*128 + dd]) * mnp[dd];
      gNM[(size_t)bid*128 + tid] = s;
    }
    __syncthreads();
    f32x4 am[4][4]; ZERO44(am);
    mm_tile<128,4>(X, Y, am, lane, wm, wn);
    const float wmv = wsm[(m*2 + b)*16 + h];
    #pragma unroll
    for (int mi = 0; mi < 4; ++mi)
      #pragma unroll
      for (int i = 0; i < 4; ++i){
        int q = wm*64 + mi*16 + rq + i;
        float f = wmv / fmaxf(gNM[(size_t)bid*128 + q], 1e-6f);
        #pragma unroll
        for (int ni = 0; ni < 4; ++ni) macc[mi][ni][i] += f * am[mi][ni][i];
      }
  }
  const float g = 1.f / (1.f + __expf(-gate[h]));
  short* op = memout + rb;
  #pragma unroll
  for (int mi = 0; mi < 4; ++mi)
    #pragma unroll
    for (int ni = 0; ni < 4; ++ni)
      #pragma unroll
      for (int i = 0; i < 4; ++i){
        int q = wm*64 + mi*16 + rq + i, e = wn*64 + ni*16 + cn;
        op[q*128 + e] = f2bf(g * macc[mi][ni][i]);
      }
}

// ---------------------------------------------------------------------------
// Pass C: local attention per (bh,chunk) + gate-combine with memout.
__global__ __launch_bounds__(256) void k_passC(const short* __restrict__ qb,
    const short* __restrict__ kin, const short* __restrict__ vin,
    const short* __restrict__ Spref, const float* __restrict__ zpref,
    const short* __restrict__ memout, const float* __restrict__ gate,
    float* __restrict__ gNL, short* __restrict__ combined){
  __shared__ short X[16384];   // sq -> masked scores
  __shared__ short Y[16384];   // sk -> Spref^T -> v^T
  const int bid = blockIdx.x, bh = bid >> 5, c = bid & 31, b = bh >> 4, h = bh & 15;
  const int tid = threadIdx.x, lane = tid & 63, wv = tid >> 6;
  const int wm = wv >> 1, wn = wv & 1;
  const int rq = (lane >> 4) * 4, cn = lane & 15;
  const size_t rb = (size_t)bid * 16384;
  const short* qp = qb + rb;
  const short* kp = kin + rb;
  const short* vp = vin + rb;

  for (int i = tid; i < 2048; i += 256){
    s16x8 a = *(const s16x8*)(qp + i*8);
    s16x8 bb = *(const s16x8*)(kp + i*8);
    s16x8 oa, ob;
    #pragma unroll
    for (int e = 0; e < 8; ++e){ oa[e] = f2bf(seplus(bf2f(a[e]))); ob[e] = f2bf(seplus(bf2f(bb[e]))); }
    *(s16x8*)(X + i*8) = oa;
    *(s16x8*)(Y + i*8) = ob;
  }
  __syncthreads();

  f32x4 sc[4][4]; ZERO44(sc);
  mm_tile<128,4>(X, Y, sc, lane, wm, wn);        // scores[q][k]
  __syncthreads();

  for (int i = tid; i < 2048; i += 256)
    *(s16x8*)(Y + i*8) = *(const s16x8*)(Spref + rb + i*8);
  if (tid < 128){
    const float* zp = zpref + (size_t)bid*128;
    float s = 0.f;
    for (int dd = 0; dd < 128; ++dd) s += bf2f(X[tid*128 + dd]) * zp[dd];
    gNL[(size_t)bid*128 + tid] = s;
  }
  __syncthreads();

  f32x4 oacc[4][4]; ZERO44(oacc);
  mm_tile<128,4>(X, Y, oacc, lane, wm, wn);      // out1[q][e] = sq @ Spref
  __syncthreads();

  // X <- masked scores (bf16), Y <- v^T
  #pragma unroll
  for (int mi = 0; mi < 4; ++mi)
    #pragma unroll
    for (int ni = 0; ni < 4; ++ni)
      #pragma unroll
      for (int i = 0; i < 4; ++i){
        int q = wm*64 + mi*16 + rq + i, k2 = wn*64 + ni*16 + cn;
        X[q*128 + k2] = f2bf((k2 <= q) ? sc[mi][ni][i] : 0.f);
      }
  const int klv = tid >> 1, dh = (tid & 1) * 64;
  #pragma unroll
  for (int j = 0; j < 8; ++j){
    s16x8 pv = *(const s16x8*)(vp + klv*128 + dh + j*8);
    #pragma unroll
    for (int e = 0; e < 8; ++e) Y[(dh + j*8 + e)*128 + klv] = pv[e];
  }
  __syncthreads();
  if (tid < 128){
    float s = gNL[(size_t)bid*128 + tid];
    for (int k2 = 0; k2 < 128; ++k2) s += bf2f(X[tid*128 + k2]);
    gNL[(size_t)bid*128 + tid] = s;
  }
  __syncthreads();

  mm_tile<128,4>(X, Y, oacc, lane, wm, wn);      // + scoresM @ v

  const float g = 1.f / (1.f + __expf(-gate[h]));
  const float og = 1.f - g;
  const short* mo = memout + rb;
  #pragma unroll
  for (int mi = 0; mi < 4; ++mi)
    #pragma unroll
    for (int ni = 0; ni < 4; ++ni)
      #pragma unroll
      for (int i = 0; i < 4; ++i){
        int q = wm*64 + mi*16 + rq + i, e = wn*64 + ni*16 + cn;
        float nl = fmaxf(gNL[(size_t)bid*128 + q], 1e-6f);
        float outv = bf2f(mo[q*128 + e]) + og * (oacc[mi][ni][i] / nl);
        combined[((size_t)b*4096 + c*128 + q)*2048 + h*128 + e] = f2bf(outv);
      }
}

// ---------------------------------------------------------------------------
extern "C" void kernel_launch(void* const* d_in, const int* in_sizes, int n_in,
                              void* d_out, int out_size, void* d_ws, size_t ws_size,
                              hipStream_t stream){
  const float* hs   = (const float*)d_in[0];
  const float* wq   = (const float*)d_in[1];
  const float* wk   = (const float*)d_in[2];
  const float* wvp  = (const float*)d_in[3];
  const float* wo   = (const float*)d_in[4];
  const float* gate = (const float*)d_in[5];
  const float* mem  = (const float*)d_in[6];
  const float* mn   = (const float*)d_in[7];
  const float* lm   = (const float*)d_in[8];
  const float* kc   = (const float*)d_in[9];

  char* base = (char*)d_ws; size_t off = 0;
  auto alloc = [&](size_t bytes)->void*{
    void* r = base + off; off = (off + bytes + 255) & ~(size_t)255; return r;
  };
  short* hs_b  = (short*)alloc(16777216ull*2);   // reused as memout after proj
  short* wq_b  = (short*)alloc(4194304ull*2);
  short* wk_b  = (short*)alloc(4194304ull*2);
  short* wv_b  = (short*)alloc(4194304ull*2);
  short* wo_b  = (short*)alloc(4194304ull*2);
  short* q_b   = (short*)alloc(16777216ull*2);
  short* k_b   = (short*)alloc(16777216ull*2);
  short* v_b   = (short*)alloc(16777216ull*2);
  short* memT  = (short*)alloc(1048576ull*2);
  float* wsm   = (float*)alloc(128*4);
  short* SZ    = (short*)alloc(16777216ull*2);   // Sc -> Spref (in place)
  float* zz    = (float*)alloc(131072ull*4);     // zc -> zpref (in place)
  float* gNL   = (float*)alloc(131072ull*4);
  float* gNM   = (float*)alloc(131072ull*4);
  short* comb  = (short*)alloc(16777216ull*2);
  float* qpart = (float*)alloc(512ull*128*4);
  short* memout = hs_b;  // alias: hs_b dead after proj GEMMs

  k_f2b4<<<4096, 256, 0, stream>>>(hs,  hs_b, 4194304);
  k_f2b4<<<1024, 256, 0, stream>>>(wq,  wq_b, 1048576);
  k_f2b4<<<1024, 256, 0, stream>>>(wk,  wk_b, 1048576);
  k_f2b4<<<1024, 256, 0, stream>>>(wvp, wv_b, 1048576);
  k_f2b4<<<1024, 256, 0, stream>>>(wo,  wo_b, 1048576);
  k_memT<<<64, 256, 0, stream>>>(mem, memT);

  k_gemm2<<<512, 512, 0, stream>>>(hs_b, wq_b, q_b, 0);
  k_gemm2<<<512, 512, 0, stream>>>(hs_b, wk_b, k_b, 0);
  k_gemm2<<<512, 512, 0, stream>>>(hs_b, wv_b, v_b, 0);

  k_qsum<<<512, 256, 0, stream>>>(q_b, qpart);
  k_relw<<<32, 128, 0, stream>>>(qpart, lm, kc, wsm);
  k_passA<<<1024, 256, 0, stream>>>(k_b, v_b, SZ, zz);
  k_scanS<<<2048, 256, 0, stream>>>(SZ);
  k_scanZ<<<16, 256, 0, stream>>>(zz);
  k_passM<<<1024, 256, 0, stream>>>(q_b, memT, mn, wsm, gate, gNM, memout);
  k_passC<<<1024, 256, 0, stream>>>(q_b, k_b, v_b, SZ, zz, memout, gate, gNL, comb);

  k_gemm2<<<512, 512, 0, stream>>>(comb, wo_b, d_out, 1);
}

// Round 5
// 661.546 us; speedup vs baseline: 1.9176x; 1.0418x over previous
//
#include <hip/hip_runtime.h>

// ---------------------------------------------------------------------------
// MultiMemoryAttention on gfx950 — bf16 MFMA pipeline.
// Shapes (hardcoded): B=2, S=4096, H=2048, nh=16, hd=128, M=4, CHUNK=128, nc=32
// R4: GEMM rebuilt on m201-class geometry: 256x256 block, 8 waves (2x4),
//   per-wave 128x64 output (8x4 frags), BK=32 per buffer, QUAD-buffered
//   (4 x 32KB = 128KB LDS), 2 phases/group x 16 MFMA, B-frags register-held,
//   3-group prefetch depth -> steady-state vmcnt(8) (drain 8->4->0 at end),
//   (row>>1)&3 colword XOR swizzle (inverse-swizzled global source),
//   bijective XCD swizzle, grid=256 (1 block/CU).
// ---------------------------------------------------------------------------

typedef __attribute__((ext_vector_type(4))) float f32x4;
typedef __attribute__((ext_vector_type(4))) int   i32x4;
typedef __attribute__((ext_vector_type(8))) short s16x8;
typedef __attribute__((ext_vector_type(4))) float fl4;
typedef __attribute__((ext_vector_type(4))) short sh4;

__device__ __forceinline__ float bf2f(short v){
  union { unsigned int u; float f; } x; x.u = ((unsigned int)(unsigned short)v) << 16; return x.f;
}
__device__ __forceinline__ short f2bf(float f){
  union { float f; unsigned int u; } x; x.f = f;
  unsigned int r = x.u + 0x7fffu + ((x.u >> 16) & 1u);
  return (short)(r >> 16);
}
__device__ __forceinline__ float seplus(float x){ return x > 0.f ? x + 1.f : __expf(x); }

__device__ __forceinline__ void mfma_bf16(f32x4& d, i32x4 a, i32x4 b){
  asm("v_mfma_f32_16x16x32_bf16 %0, %1, %2, %0" : "+v"(d) : "v"(a), "v"(b));
}

__device__ __forceinline__ void gload_lds16(const void* g, void* l){
  __builtin_amdgcn_global_load_lds((__attribute__((address_space(1))) unsigned int*)(g),
                                   (__attribute__((address_space(3))) unsigned int*)(l), 16, 0, 0);
}

// Legacy simple tile-matmul (used by the small pass kernels; unchanged).
template<int LDK, int NKK>
__device__ __forceinline__ void mm_tile(const short* Ab, const short* Bb,
                                        f32x4 (&acc)[4][4], int lane, int wm, int wn){
  const int r = lane & 15, ks8 = (lane >> 4) * 8;
  #pragma unroll
  for (int kk = 0; kk < NKK; ++kk){
    i32x4 a[4], b[4];
    #pragma unroll
    for (int mi = 0; mi < 4; ++mi)
      a[mi] = *(const i32x4*)(Ab + (wm*64 + mi*16 + r)*LDK + kk*32 + ks8);
    #pragma unroll
    for (int ni = 0; ni < 4; ++ni)
      b[ni] = *(const i32x4*)(Bb + (wn*64 + ni*16 + r)*LDK + kk*32 + ks8);
    #pragma unroll
    for (int mi = 0; mi < 4; ++mi)
      #pragma unroll
      for (int ni = 0; ni < 4; ++ni)
        mfma_bf16(acc[mi][ni], a[mi], b[ni]);
  }
}

#define ZERO44(A) do { _Pragma("unroll") for (int _i=0;_i<4;++_i){ _Pragma("unroll") for (int _j=0;_j<4;++_j){ A[_i][_j][0]=0.f;A[_i][_j][1]=0.f;A[_i][_j][2]=0.f;A[_i][_j][3]=0.f; } } } while(0)

// ---------------------------------------------------------------------------
// fp32 -> bf16 convert, float4-vectorized
__global__ __launch_bounds__(256) void k_f2b4(const float* __restrict__ s,
                                              short* __restrict__ d, int n4){
  int i = blockIdx.x*256 + threadIdx.x, st = gridDim.x*256;
  for (; i < n4; i += st){
    fl4 v = ((const fl4*)s)[i];
    sh4 o;
    #pragma unroll
    for (int j = 0; j < 4; ++j) o[j] = f2bf(v[j]);
    ((sh4*)d)[i] = o;
  }
}

// memories [M,nh,hd,hd] fp32 -> memT [M*nh][e][d] bf16 (transposed)
__global__ __launch_bounds__(256) void k_memT(const float* __restrict__ mem,
                                              short* __restrict__ memT){
  const int mh = blockIdx.x;
  const float* s = mem + (size_t)mh*16384;
  short* d = memT + (size_t)mh*16384;
  for (int i = threadIdx.x; i < 16384; i += 256){
    int dd = i >> 7, e = i & 127;
    d[e*128 + dd] = f2bf(s[i]);
  }
}

// ---------------------------------------------------------------------------
// Pipelined GEMM: C[8192,2048] = A[8192,2048] @ B[2048,2048]^T (bf16, BT form).
// 256x256 block tile, 512 threads (8 waves 2x4), per-wave 128x64 output.
// K split into 64 groups of 32; quad-buffered LDS ring (4 x 32KB).
// Ledger (loads FIFO, 4 per group: A-r0,A-r1 then B-r0,B-r1):
//   prologue: stage S0,S1,S2 (12 loads), vmcnt(8) retires S0.
//   group g: ph0 stages A of S(g+3), ph1 stages B of S(g+3) (g<=60);
//   end-of-group vmcnt(8) retires exactly S(g+1); g=61: vmcnt(4); g=62: vmcnt(0).
// mode 0: bf16 out scattered to [B,nh,S,hd]; mode 1: fp32 out row-major.
__global__ __launch_bounds__(512, 2) void k_gemm2(const short* __restrict__ A,
                                                  const short* __restrict__ B,
                                                  void* __restrict__ outp, int mode){
  __shared__ short lds_[65536];                 // 128 KB = 4 bufs x (16KB A + 16KB B)
  const int tid = threadIdx.x, lane = tid & 63, w = tid >> 6;
  const int wr = w >> 2, wc = w & 3;            // 2 x 4 wave grid
  const int bid = blockIdx.x;
  const int swz = (bid & 7) * 32 + (bid >> 3);  // XCD swizzle (256 % 8 == 0, bijective)
  const int bm = swz >> 3, bn = swz & 7;        // 32 x 8 tile grid

  // ---- staging: row = tid>>2 (0..127) (+128 for round 1), colword = tid&3.
  // LDS phys colword cw holds global elements ((cw ^ ((row>>1)&3))*8 ..+7):
  // inverse-swizzle the global source, LDS dest stays linear (lane*16).
  const int grow = tid >> 2;
  const int scole = ((tid & 3) ^ ((tid >> 3) & 3)) << 3;     // (row>>1)&3 = (tid>>3)&3
  const short* gA0 = A + ((size_t)(bm*256 +       grow))*2048 + scole;
  const short* gA1 = A + ((size_t)(bm*256 + 128 + grow))*2048 + scole;
  const short* gB0 = B + ((size_t)(bn*256 +       grow))*2048 + scole;
  const short* gB1 = B + ((size_t)(bn*256 + 128 + grow))*2048 + scole;
  const int ldsw = w * 1024;                    // wave-uniform offset within a round

  #define BUFB(s) ((char*)lds_ + ((s) << 15))
  #define STGA(s, g) do { gload_lds16(gA0 + (size_t)(g)*32, BUFB(s) +        ldsw); \
                          gload_lds16(gA1 + (size_t)(g)*32, BUFB(s) + 8192 + ldsw); } while(0)
  #define STGB(s, g) do { gload_lds16(gB0 + (size_t)(g)*32, BUFB(s) + 16384 +        ldsw); \
                          gload_lds16(gB1 + (size_t)(g)*32, BUFB(s) + 16384 + 8192 + ldsw); } while(0)

  // ---- frag read byte offsets (within buffer); row stride 64 B (K=32).
  const int fr = lane & 15, fg = lane >> 4;
  const int xw = (fr >> 1) & 3;                 // (row>>1)&3 == (fr>>1)&3 (rows % 16 aligned)
  int aoffb[8], boffb[4];
  #pragma unroll
  for (int mi = 0; mi < 8; ++mi)
    aoffb[mi] = (wr*128 + mi*16 + fr)*64 + ((fg ^ xw) << 4);
  #pragma unroll
  for (int ni = 0; ni < 4; ++ni)
    boffb[ni] = 16384 + (wc*64 + ni*16 + fr)*64 + ((fg ^ xw) << 4);

  f32x4 acc[8][4];
  #pragma unroll
  for (int i = 0; i < 8; ++i)
    #pragma unroll
    for (int j = 0; j < 4; ++j){ acc[i][j][0]=0.f; acc[i][j][1]=0.f; acc[i][j][2]=0.f; acc[i][j][3]=0.f; }

  // ---- prologue: stage S0, S1, S2 (12 loads) ----
  STGA(0,0); STGB(0,0);
  STGA(1,1); STGB(1,1);
  STGA(2,2); STGB(2,2);
  asm volatile("s_waitcnt vmcnt(8)" ::: "memory");   // S0 resident
  __builtin_amdgcn_s_barrier();

  #pragma unroll 1
  for (int g = 0; g < 64; ++g){
    const char* cb = BUFB(g & 3);
    const int ts = (g + 3) & 3;
    const bool st = (g <= 60);

    // ===== phase 0: B-frags (held all group) + A-frags mi 0-3 =====
    i32x4 bfr[4], afr[4];
    #pragma unroll
    for (int ni = 0; ni < 4; ++ni) bfr[ni] = *(const i32x4*)(cb + boffb[ni]);
    #pragma unroll
    for (int mi = 0; mi < 4; ++mi) afr[mi] = *(const i32x4*)(cb + aoffb[mi]);
    if (st) STGA(ts, g + 3);
    __builtin_amdgcn_s_barrier();
    asm volatile("s_waitcnt lgkmcnt(0)" ::: "memory");
    __builtin_amdgcn_sched_barrier(0);
    __builtin_amdgcn_s_setprio(1);
    #pragma unroll
    for (int mi = 0; mi < 4; ++mi)
      #pragma unroll
      for (int ni = 0; ni < 4; ++ni)
        mfma_bf16(acc[mi][ni], afr[mi], bfr[ni]);
    __builtin_amdgcn_s_setprio(0);
    __builtin_amdgcn_s_barrier();

    // ===== phase 1: A-frags mi 4-7 =====
    #pragma unroll
    for (int mi = 0; mi < 4; ++mi) afr[mi] = *(const i32x4*)(cb + aoffb[4 + mi]);
    if (st) STGB(ts, g + 3);
    __builtin_amdgcn_s_barrier();
    asm volatile("s_waitcnt lgkmcnt(0)" ::: "memory");
    __builtin_amdgcn_sched_barrier(0);
    __builtin_amdgcn_s_setprio(1);
    #pragma unroll
    for (int mi = 0; mi < 4; ++mi)
      #pragma unroll
      for (int ni = 0; ni < 4; ++ni)
        mfma_bf16(acc[4 + mi][ni], afr[mi], bfr[ni]);
    __builtin_amdgcn_s_setprio(0);
    // group boundary: counted wait retires exactly S(g+1); S(g+2),S(g+3) stay in flight.
    if (g <= 60)       asm volatile("s_waitcnt vmcnt(8)" ::: "memory");
    else if (g == 61)  asm volatile("s_waitcnt vmcnt(4)" ::: "memory");
    else if (g == 62)  asm volatile("s_waitcnt vmcnt(0)" ::: "memory");
    __builtin_amdgcn_s_barrier();
  }

  // ---- epilogue ----
  const int rq = fg * 4, cn = fr;
  if (mode == 0){
    short* o = (short*)outp;
    #pragma unroll
    for (int mi = 0; mi < 8; ++mi)
      #pragma unroll
      for (int ni = 0; ni < 4; ++ni)
        #pragma unroll
        for (int i = 0; i < 4; ++i){
          int mrow = bm*256 + wr*128 + mi*16 + rq + i;
          int ncol = bn*256 + wc*64 + ni*16 + cn;
          int b = mrow >> 12, s = mrow & 4095, h = ncol >> 7, dd = ncol & 127;
          o[((size_t)(b*16 + h)*4096 + s)*128 + dd] = f2bf(acc[mi][ni][i]);
        }
  } else {
    float* o = (float*)outp;
    #pragma unroll
    for (int mi = 0; mi < 8; ++mi)
      #pragma unroll
      for (int ni = 0; ni < 4; ++ni)
        #pragma unroll
        for (int i = 0; i < 4; ++i){
          int mrow = bm*256 + wr*128 + mi*16 + rq + i;
          int ncol = bn*256 + wc*64 + ni*16 + cn;
          o[(size_t)mrow*2048 + ncol] = acc[mi][ni][i];
        }
  }
  #undef BUFB
  #undef STGA
  #undef STGB
}

// ---------------------------------------------------------------------------
// qsum pass: partial[bh*16+sl][d] = sum over 256 rows of q (vectorized).
__global__ __launch_bounds__(256) void k_qsum(const short* __restrict__ qb,
                                              float* __restrict__ partial){
  const int bid = blockIdx.x, bh = bid >> 4, sl = bid & 15;
  const int t = threadIdx.x, dvec = t & 15, rg = t >> 4;
  const short* qp = qb + (size_t)bh*4096*128 + (size_t)sl*256*128;
  float acc[8];
  #pragma unroll
  for (int e = 0; e < 8; ++e) acc[e] = 0.f;
  for (int r = 0; r < 16; ++r){
    s16x8 v = *(const s16x8*)(qp + (rg*16 + r)*128 + dvec*8);
    #pragma unroll
    for (int e = 0; e < 8; ++e) acc[e] += bf2f(v[e]);
  }
  __shared__ float red[16][128];
  #pragma unroll
  for (int e = 0; e < 8; ++e) red[rg][dvec*8 + e] = acc[e];
  __syncthreads();
  if (t < 128){
    float s = 0.f;
    #pragma unroll
    for (int r = 0; r < 16; ++r) s += red[r][t];
    partial[(size_t)bid*128 + t] = s;
  }
}

// rel + softmax over memories from qsum partials. One block per (b,h).
__global__ __launch_bounds__(128) void k_relw(const float* __restrict__ partial,
                                              const float* __restrict__ lm,
                                              const float* __restrict__ kc,
                                              float* __restrict__ wsm){
  const int bh = blockIdx.x, b = bh >> 4, h = bh & 15, t = threadIdx.x;
  __shared__ float tmp[128];
  __shared__ float relv[4];
  float qs = 0.f;
  #pragma unroll
  for (int sl = 0; sl < 16; ++sl) qs += partial[((size_t)bh*16 + sl)*128 + t];
  for (int m = 0; m < 4; ++m){
    tmp[t] = qs * lm[(m*16 + h)*128 + t];
    __syncthreads();
    for (int o = 64; o > 0; o >>= 1){ if (t < o) tmp[t] += tmp[t+o]; __syncthreads(); }
    if (t == 0) relv[m] = tmp[0] * (1.f/4096.f);
    __syncthreads();
  }
  if (t == 0){
    float w[4]; float mx = -1e30f;
    for (int m = 0; m < 4; ++m){
      float s = 0.f;
      for (int hh = 0; hh < 16; ++hh) s += kc[m*16 + hh];
      w[m] = (s >= 1e-6f) ? relv[m] : -1e30f;
      mx = fmaxf(mx, w[m]);
    }
    float den = 0.f;
    for (int m = 0; m < 4; ++m){ w[m] = __expf(w[m] - mx); den += w[m]; }
    for (int m = 0; m < 4; ++m) wsm[(m*2 + b)*16 + h] = w[m] / den;
  }
}

// ---------------------------------------------------------------------------
// Pass A: per-chunk Sc^T[e][d] = sum_k v[k][e]*sk[k][d] (bf16) and zc[d].
__global__ __launch_bounds__(256) void k_passA(const short* __restrict__ kin,
                                               const short* __restrict__ vin,
                                               short* __restrict__ Sc,
                                               float* __restrict__ zc){
  __shared__ short skT[128*128];
  __shared__ short vT[128*128];
  const int bid = blockIdx.x;                 // bh*32 + c
  const int tid = threadIdx.x, lane = tid & 63, wv = tid >> 6;
  const int wm = wv >> 1, wn = wv & 1;
  const size_t rb = (size_t)bid * 16384;
  const short* kp = kin + rb;
  const short* vp = vin + rb;
  const int kl = tid >> 1, dh = (tid & 1) * 64;
  #pragma unroll
  for (int j = 0; j < 8; ++j){
    s16x8 pk = *(const s16x8*)(kp + kl*128 + dh + j*8);
    s16x8 pv = *(const s16x8*)(vp + kl*128 + dh + j*8);
    #pragma unroll
    for (int e = 0; e < 8; ++e){
      int dd = dh + j*8 + e;
      skT[dd*128 + kl] = f2bf(seplus(bf2f(pk[e])));
      vT [dd*128 + kl] = pv[e];
    }
  }
  __syncthreads();
  if (tid < 128){
    float z = 0.f;
    for (int k2 = 0; k2 < 128; ++k2) z += bf2f(skT[tid*128 + k2]);
    zc[(size_t)bid*128 + tid] = z;
  }
  f32x4 acc[4][4]; ZERO44(acc);
  mm_tile<128,4>(vT, skT, acc, lane, wm, wn);
  short* o = Sc + rb;
  const int rq = (lane >> 4) * 4, cn = lane & 15;
  #pragma unroll
  for (int mi = 0; mi < 4; ++mi)
    #pragma unroll
    for (int ni = 0; ni < 4; ++ni)
      #pragma unroll
      for (int i = 0; i < 4; ++i){
        int e = wm*64 + mi*16 + rq + i, d = wn*64 + ni*16 + cn;
        o[e*128 + d] = f2bf(acc[mi][ni][i]);
      }
}

// Pass B (parallel): exclusive prefix over 32 chunks, one thread per element.
__global__ __launch_bounds__(256) void k_scanS(short* __restrict__ S){
  const int gid = blockIdx.x*256 + threadIdx.x;       // < 524288
  const int bh = gid >> 14, elem = gid & 16383;
  short* p = S + (size_t)bh*32*16384 + elem;
  float a[32];
  #pragma unroll
  for (int c = 0; c < 32; ++c) a[c] = bf2f(p[(size_t)c*16384]);
  float run = 0.f;
  #pragma unroll
  for (int c = 0; c < 32; ++c){ float cur = a[c]; p[(size_t)c*16384] = f2bf(run); run += cur; }
}

__global__ __launch_bounds__(256) void k_scanZ(float* __restrict__ z){
  const int gid = blockIdx.x*256 + threadIdx.x;       // < 4096
  const int bh = gid >> 7, d = gid & 127;
  float* p = z + (size_t)bh*32*128 + d;
  float a[32];
  #pragma unroll
  for (int c = 0; c < 32; ++c) a[c] = p[c*128];
  float run = 0.f;
  #pragma unroll
  for (int c = 0; c < 32; ++c){ float cur = a[c]; p[c*128] = run; run += cur; }
}

// ---------------------------------------------------------------------------
// Pass M: memory retrieval, writes g*sum_m w_m*(sq@mem_m)/max(norm_m,eps).
__global__ __launch_bounds__(256) void k_passM(const short* __restrict__ qb,
    const short* __restrict__ memT, const float* __restrict__ mn,
    const float* __restrict__ wsm, const float* __restrict__ gate,
    float* __restrict__ gNM, short* __restrict__ memout){
  __shared__ short X[16384];
  __shared__ short Y[16384];
  const int bid = blockIdx.x, bh = bid >> 5, b = bh >> 4, h = bh & 15;
  const int tid = threadIdx.x, lane = tid & 63, wv = tid >> 6;
  const int wm = wv >> 1, wn = wv & 1;
  const int rq = (lane >> 4) * 4, cn = lane & 15;
  const size_t rb = (size_t)bid * 16384;
  const short* qp = qb + rb;
  for (int i = tid; i < 2048; i += 256){
    s16x8 v = *(const s16x8*)(qp + i*8);
    s16x8 o;
    #pragma unroll
    for (int e = 0; e < 8; ++e) o[e] = f2bf(seplus(bf2f(v[e])));
    *(s16x8*)(X + i*8) = o;
  }
  f32x4 macc[4][4]; ZERO44(macc);
  for (int m = 0; m < 4; ++m){
    __syncthreads();   // X ready (m=0); Y/NM reads of prior iter done
    const short* mt = memT + (size_t)(m*16 + h)*16384;
    for (int i = tid; i < 2048; i += 256)
      *(s16x8*)(Y + i*8) = *(const s16x8*)(mt + i*8);
    if (tid < 128){
      const float* mnp = mn + (m*16 + h)*128;
      float s = 0.f;
      for (int dd = 0; dd < 128; ++dd) s += bf2f(X[tid*128 + dd]) * mnp[dd];
      gNM[(size_t)bid*128 + tid] = s;
    }
    __syncthreads();
    f32x4 am[4][4]; ZERO44(am);
    mm_tile<128,4>(X, Y, am, lane, wm, wn);
    const float wmv = wsm[(m*2 + b)*16 + h];
    #pragma unroll
    for (int mi = 0; mi < 4; ++mi)
      #pragma unroll
      for (int i = 0; i < 4; ++i){
        int q = wm*64 + mi*16 + rq + i;
        float f = wmv / fmaxf(gNM[(size_t)bid*128 + q], 1e-6f);
        #pragma unroll
        for (int ni = 0; ni < 4; ++ni) macc[mi][ni][i] += f * am[mi][ni][i];
      }
  }
  const float g = 1.f / (1.f + __expf(-gate[h]));
  short* op = memout + rb;
  #pragma unroll
  for (int mi = 0; mi < 4; ++mi)
    #pragma unroll
    for (int ni = 0; ni < 4; ++ni)
      #pragma unroll
      for (int i = 0; i < 4; ++i){
        int q = wm*64 + mi*16 + rq + i, e = wn*64 + ni*16 + cn;
        op[q*128 + e] = f2bf(g * macc[mi][ni][i]);
      }
}

// ---------------------------------------------------------------------------
// Pass C: local attention per (bh,chunk) + gate-combine with memout.
__global__ __launch_bounds__(256) void k_passC(const short* __restrict__ qb,
    const short* __restrict__ kin, const short* __restrict__ vin,
    const short* __restrict__ Spref, const float* __restrict__ zpref,
    const short* __restrict__ memout, const float* __restrict__ gate,
    float* __restrict__ gNL, short* __restrict__ combined){
  __shared__ short X[16384];   // sq -> masked scores
  __shared__ short Y[16384];   // sk -> Spref^T -> v^T
  const int bid = blockIdx.x, bh = bid >> 5, c = bid & 31, b = bh >> 4, h = bh & 15;
  const int tid = threadIdx.x, lane = tid & 63, wv = tid >> 6;
  const int wm = wv >> 1, wn = wv & 1;
  const int rq = (lane >> 4) * 4, cn = lane & 15;
  const size_t rb = (size_t)bid * 16384;
  const short* qp = qb + rb;
  const short* kp = kin + rb;
  const short* vp = vin + rb;

  for (int i = tid; i < 2048; i += 256){
    s16x8 a = *(const s16x8*)(qp + i*8);
    s16x8 bb = *(const s16x8*)(kp + i*8);
    s16x8 oa, ob;
    #pragma unroll
    for (int e = 0; e < 8; ++e){ oa[e] = f2bf(seplus(bf2f(a[e]))); ob[e] = f2bf(seplus(bf2f(bb[e]))); }
    *(s16x8*)(X + i*8) = oa;
    *(s16x8*)(Y + i*8) = ob;
  }
  __syncthreads();

  f32x4 sc[4][4]; ZERO44(sc);
  mm_tile<128,4>(X, Y, sc, lane, wm, wn);        // scores[q][k]
  __syncthreads();

  for (int i = tid; i < 2048; i += 256)
    *(s16x8*)(Y + i*8) = *(const s16x8*)(Spref + rb + i*8);
  if (tid < 128){
    const float* zp = zpref + (size_t)bid*128;
    float s = 0.f;
    for (int dd = 0; dd < 128; ++dd) s += bf2f(X[tid*128 + dd]) * zp[dd];
    gNL[(size_t)bid*128 + tid] = s;
  }
  __syncthreads();

  f32x4 oacc[4][4]; ZERO44(oacc);
  mm_tile<128,4>(X, Y, oacc, lane, wm, wn);      // out1[q][e] = sq @ Spref
  __syncthreads();

  // X <- masked scores (bf16), Y <- v^T
  #pragma unroll
  for (int mi = 0; mi < 4; ++mi)
    #pragma unroll
    for (int ni = 0; ni < 4; ++ni)
      #pragma unroll
      for (int i = 0; i < 4; ++i){
        int q = wm*64 + mi*16 + rq + i, k2 = wn*64 + ni*16 + cn;
        X[q*128 + k2] = f2bf((k2 <= q) ? sc[mi][ni][i] : 0.f);
      }
  const int klv = tid >> 1, dh = (tid & 1) * 64;
  #pragma unroll
  for (int j = 0; j < 8; ++j){
    s16x8 pv = *(const s16x8*)(vp + klv*128 + dh + j*8);
    #pragma unroll
    for (int e = 0; e < 8; ++e) Y[(dh + j*8 + e)*128 + klv] = pv[e];
  }
  __syncthreads();
  if (tid < 128){
    float s = gNL[(size_t)bid*128 + tid];
    for (int k2 = 0; k2 < 128; ++k2) s += bf2f(X[tid*128 + k2]);
    gNL[(size_t)bid*128 + tid] = s;
  }
  __syncthreads();

  mm_tile<128,4>(X, Y, oacc, lane, wm, wn);      // + scoresM @ v

  const float g = 1.f / (1.f + __expf(-gate[h]));
  const float og = 1.f - g;
  const short* mo = memout + rb;
  #pragma unroll
  for (int mi = 0; mi < 4; ++mi)
    #pragma unroll
    for (int ni = 0; ni < 4; ++ni)
      #pragma unroll
      for (int i = 0; i < 4; ++i){
        int q = wm*64 + mi*16 + rq + i, e = wn*64 + ni*16 + cn;
        float nl = fmaxf(gNL[(size_t)bid*128 + q], 1e-6f);
        float outv = bf2f(mo[q*128 + e]) + og * (oacc[mi][ni][i] / nl);
        combined[((size_t)b*4096 + c*128 + q)*2048 + h*128 + e] = f2bf(outv);
      }
}

// ---------------------------------------------------------------------------
extern "C" void kernel_launch(void* const* d_in, const int* in_sizes, int n_in,
                              void* d_out, int out_size, void* d_ws, size_t ws_size,
                              hipStream_t stream){
  const float* hs   = (const float*)d_in[0];
  const float* wq   = (const float*)d_in[1];
  const float* wk   = (const float*)d_in[2];
  const float* wvp  = (const float*)d_in[3];
  const float* wo   = (const float*)d_in[4];
  const float* gate = (const float*)d_in[5];
  const float* mem  = (const float*)d_in[6];
  const float* mn   = (const float*)d_in[7];
  const float* lm   = (const float*)d_in[8];
  const float* kc   = (const float*)d_in[9];

  char* base = (char*)d_ws; size_t off = 0;
  auto alloc = [&](size_t bytes)->void*{
    void* r = base + off; off = (off + bytes + 255) & ~(size_t)255; return r;
  };
  short* hs_b  = (short*)alloc(16777216ull*2);   // reused as memout after proj
  short* wq_b  = (short*)alloc(4194304ull*2);
  short* wk_b  = (short*)alloc(4194304ull*2);
  short* wv_b  = (short*)alloc(4194304ull*2);
  short* wo_b  = (short*)alloc(4194304ull*2);
  short* q_b   = (short*)alloc(16777216ull*2);
  short* k_b   = (short*)alloc(16777216ull*2);
  short* v_b   = (short*)alloc(16777216ull*2);
  short* memT  = (short*)alloc(1048576ull*2);
  float* wsm   = (float*)alloc(128*4);
  short* SZ    = (short*)alloc(16777216ull*2);   // Sc -> Spref (in place)
  float* zz    = (float*)alloc(131072ull*4);     // zc -> zpref (in place)
  float* gNL   = (float*)alloc(131072ull*4);
  float* gNM   = (float*)alloc(131072ull*4);
  short* comb  = (short*)alloc(16777216ull*2);
  float* qpart = (float*)alloc(512ull*128*4);
  short* memout = hs_b;  // alias: hs_b dead after proj GEMMs

  k_f2b4<<<4096, 256, 0, stream>>>(hs,  hs_b, 4194304);
  k_f2b4<<<1024, 256, 0, stream>>>(wq,  wq_b, 1048576);
  k_f2b4<<<1024, 256, 0, stream>>>(wk,  wk_b, 1048576);
  k_f2b4<<<1024, 256, 0, stream>>>(wvp, wv_b, 1048576);
  k_f2b4<<<1024, 256, 0, stream>>>(wo,  wo_b, 1048576);
  k_memT<<<64, 256, 0, stream>>>(mem, memT);

  k_gemm2<<<256, 512, 0, stream>>>(hs_b, wq_b, q_b, 0);
  k_gemm2<<<256, 512, 0, stream>>>(hs_b, wk_b, k_b, 0);
  k_gemm2<<<256, 512, 0, stream>>>(hs_b, wv_b, v_b, 0);

  k_qsum<<<512, 256, 0, stream>>>(q_b, qpart);
  k_relw<<<32, 128, 0, stream>>>(qpart, lm, kc, wsm);
  k_passA<<<1024, 256, 0, stream>>>(k_b, v_b, SZ, zz);
  k_scanS<<<2048, 256, 0, stream>>>(SZ);
  k_scanZ<<<16, 256, 0, stream>>>(zz);
  k_passM<<<1024, 256, 0, stream>>>(q_b, memT, mn, wsm, gate, gNM, memout);
  k_passC<<<1024, 256, 0, stream>>>(q_b, k_b, v_b, SZ, zz, memout, gate, gNL, comb);

  k_gemm2<<<256, 512, 0, stream>>>(comb, wo_b, d_out, 1);
}

// Round 6
// 617.552 us; speedup vs baseline: 2.0542x; 1.0712x over previous
//
#include <hip/hip_runtime.h>

// ---------------------------------------------------------------------------
// MultiMemoryAttention on gfx950 — bf16 MFMA pipeline.
// Shapes (hardcoded): B=2, S=4096, H=2048, nh=16, hd=128, M=4, CHUNK=128, nc=32
// R5: pass kernels de-conflicted:
//   - 128-col LDS tiles swizzled (elem col ^= (row&7)<<3) on write AND read
//     (mm_tile_swz) -> 16-way ds_read_b128 conflicts -> 2-way (free).
//   - serial per-thread 128-iter column loops (z-sum / norm-dot / row-sum)
//     replaced by 2-thread/row vectorized swizzled reads + shfl_xor combine.
//   - gNM/gNL moved to __shared__.
// GEMM (R4 structure) unchanged.
// ---------------------------------------------------------------------------

typedef __attribute__((ext_vector_type(4))) float f32x4;
typedef __attribute__((ext_vector_type(4))) int   i32x4;
typedef __attribute__((ext_vector_type(8))) short s16x8;
typedef __attribute__((ext_vector_type(4))) float fl4;
typedef __attribute__((ext_vector_type(4))) short sh4;

__device__ __forceinline__ float bf2f(short v){
  union { unsigned int u; float f; } x; x.u = ((unsigned int)(unsigned short)v) << 16; return x.f;
}
__device__ __forceinline__ short f2bf(float f){
  union { float f; unsigned int u; } x; x.f = f;
  unsigned int r = x.u + 0x7fffu + ((x.u >> 16) & 1u);
  return (short)(r >> 16);
}
__device__ __forceinline__ float seplus(float x){ return x > 0.f ? x + 1.f : __expf(x); }

__device__ __forceinline__ void mfma_bf16(f32x4& d, i32x4 a, i32x4 b){
  asm("v_mfma_f32_16x16x32_bf16 %0, %1, %2, %0" : "+v"(d) : "v"(a), "v"(b));
}

__device__ __forceinline__ void gload_lds16(const void* g, void* l){
  __builtin_amdgcn_global_load_lds((__attribute__((address_space(1))) unsigned int*)(g),
                                   (__attribute__((address_space(3))) unsigned int*)(l), 16, 0, 0);
}

// Swizzled tile-matmul for 128-col LDS tiles: element col ^= (row&7)<<3.
// Row of every fragment is (multiple of 16) + (lane&15), so row&7 = lane&7.
template<int LDK, int NKK>
__device__ __forceinline__ void mm_tile_swz(const short* Ab, const short* Bb,
                                            f32x4 (&acc)[4][4], int lane, int wm, int wn){
  const int r = lane & 15, ks8 = (lane >> 4) * 8;
  const int sx = (r & 7) << 3;
  #pragma unroll
  for (int kk = 0; kk < NKK; ++kk){
    i32x4 a[4], b[4];
    #pragma unroll
    for (int mi = 0; mi < 4; ++mi)
      a[mi] = *(const i32x4*)(Ab + (wm*64 + mi*16 + r)*LDK + ((kk*32 + ks8) ^ sx));
    #pragma unroll
    for (int ni = 0; ni < 4; ++ni)
      b[ni] = *(const i32x4*)(Bb + (wn*64 + ni*16 + r)*LDK + ((kk*32 + ks8) ^ sx));
    #pragma unroll
    for (int mi = 0; mi < 4; ++mi)
      #pragma unroll
      for (int ni = 0; ni < 4; ++ni)
        mfma_bf16(acc[mi][ni], a[mi], b[ni]);
  }
}

#define ZERO44(A) do { _Pragma("unroll") for (int _i=0;_i<4;++_i){ _Pragma("unroll") for (int _j=0;_j<4;++_j){ A[_i][_j][0]=0.f;A[_i][_j][1]=0.f;A[_i][_j][2]=0.f;A[_i][_j][3]=0.f; } } } while(0)

// ---------------------------------------------------------------------------
// fp32 -> bf16 convert, float4-vectorized
__global__ __launch_bounds__(256) void k_f2b4(const float* __restrict__ s,
                                              short* __restrict__ d, int n4){
  int i = blockIdx.x*256 + threadIdx.x, st = gridDim.x*256;
  for (; i < n4; i += st){
    fl4 v = ((const fl4*)s)[i];
    sh4 o;
    #pragma unroll
    for (int j = 0; j < 4; ++j) o[j] = f2bf(v[j]);
    ((sh4*)d)[i] = o;
  }
}

// memories [M,nh,hd,hd] fp32 -> memT [M*nh][e][d] bf16 (transposed)
__global__ __launch_bounds__(256) void k_memT(const float* __restrict__ mem,
                                              short* __restrict__ memT){
  const int mh = blockIdx.x;
  const float* s = mem + (size_t)mh*16384;
  short* d = memT + (size_t)mh*16384;
  for (int i = threadIdx.x; i < 16384; i += 256){
    int dd = i >> 7, e = i & 127;
    d[e*128 + dd] = f2bf(s[i]);
  }
}

// ---------------------------------------------------------------------------
// Pipelined GEMM (R4 structure, unchanged): 256x256 block, 8 waves, quad-buf,
// counted vmcnt(8), (row>>1)&3 colword swizzle, bijective XCD swizzle.
__global__ __launch_bounds__(512, 2) void k_gemm2(const short* __restrict__ A,
                                                  const short* __restrict__ B,
                                                  void* __restrict__ outp, int mode){
  __shared__ short lds_[65536];                 // 128 KB = 4 bufs x (16KB A + 16KB B)
  const int tid = threadIdx.x, lane = tid & 63, w = tid >> 6;
  const int wr = w >> 2, wc = w & 3;            // 2 x 4 wave grid
  const int bid = blockIdx.x;
  const int swz = (bid & 7) * 32 + (bid >> 3);  // XCD swizzle (256 % 8 == 0, bijective)
  const int bm = swz >> 3, bn = swz & 7;        // 32 x 8 tile grid

  const int grow = tid >> 2;
  const int scole = ((tid & 3) ^ ((tid >> 3) & 3)) << 3;
  const short* gA0 = A + ((size_t)(bm*256 +       grow))*2048 + scole;
  const short* gA1 = A + ((size_t)(bm*256 + 128 + grow))*2048 + scole;
  const short* gB0 = B + ((size_t)(bn*256 +       grow))*2048 + scole;
  const short* gB1 = B + ((size_t)(bn*256 + 128 + grow))*2048 + scole;
  const int ldsw = w * 1024;

  #define BUFB(s) ((char*)lds_ + ((s) << 15))
  #define STGA(s, g) do { gload_lds16(gA0 + (size_t)(g)*32, BUFB(s) +        ldsw); \
                          gload_lds16(gA1 + (size_t)(g)*32, BUFB(s) + 8192 + ldsw); } while(0)
  #define STGB(s, g) do { gload_lds16(gB0 + (size_t)(g)*32, BUFB(s) + 16384 +        ldsw); \
                          gload_lds16(gB1 + (size_t)(g)*32, BUFB(s) + 16384 + 8192 + ldsw); } while(0)

  const int fr = lane & 15, fg = lane >> 4;
  const int xw = (fr >> 1) & 3;
  int aoffb[8], boffb[4];
  #pragma unroll
  for (int mi = 0; mi < 8; ++mi)
    aoffb[mi] = (wr*128 + mi*16 + fr)*64 + ((fg ^ xw) << 4);
  #pragma unroll
  for (int ni = 0; ni < 4; ++ni)
    boffb[ni] = 16384 + (wc*64 + ni*16 + fr)*64 + ((fg ^ xw) << 4);

  f32x4 acc[8][4];
  #pragma unroll
  for (int i = 0; i < 8; ++i)
    #pragma unroll
    for (int j = 0; j < 4; ++j){ acc[i][j][0]=0.f; acc[i][j][1]=0.f; acc[i][j][2]=0.f; acc[i][j][3]=0.f; }

  STGA(0,0); STGB(0,0);
  STGA(1,1); STGB(1,1);
  STGA(2,2); STGB(2,2);
  asm volatile("s_waitcnt vmcnt(8)" ::: "memory");
  __builtin_amdgcn_s_barrier();

  #pragma unroll 1
  for (int g = 0; g < 64; ++g){
    const char* cb = BUFB(g & 3);
    const int ts = (g + 3) & 3;
    const bool st = (g <= 60);

    i32x4 bfr[4], afr[4];
    #pragma unroll
    for (int ni = 0; ni < 4; ++ni) bfr[ni] = *(const i32x4*)(cb + boffb[ni]);
    #pragma unroll
    for (int mi = 0; mi < 4; ++mi) afr[mi] = *(const i32x4*)(cb + aoffb[mi]);
    if (st) STGA(ts, g + 3);
    __builtin_amdgcn_s_barrier();
    asm volatile("s_waitcnt lgkmcnt(0)" ::: "memory");
    __builtin_amdgcn_sched_barrier(0);
    __builtin_amdgcn_s_setprio(1);
    #pragma unroll
    for (int mi = 0; mi < 4; ++mi)
      #pragma unroll
      for (int ni = 0; ni < 4; ++ni)
        mfma_bf16(acc[mi][ni], afr[mi], bfr[ni]);
    __builtin_amdgcn_s_setprio(0);
    __builtin_amdgcn_s_barrier();

    #pragma unroll
    for (int mi = 0; mi < 4; ++mi) afr[mi] = *(const i32x4*)(cb + aoffb[4 + mi]);
    if (st) STGB(ts, g + 3);
    __builtin_amdgcn_s_barrier();
    asm volatile("s_waitcnt lgkmcnt(0)" ::: "memory");
    __builtin_amdgcn_sched_barrier(0);
    __builtin_amdgcn_s_setprio(1);
    #pragma unroll
    for (int mi = 0; mi < 4; ++mi)
      #pragma unroll
      for (int ni = 0; ni < 4; ++ni)
        mfma_bf16(acc[4 + mi][ni], afr[mi], bfr[ni]);
    __builtin_amdgcn_s_setprio(0);
    if (g <= 60)       asm volatile("s_waitcnt vmcnt(8)" ::: "memory");
    else if (g == 61)  asm volatile("s_waitcnt vmcnt(4)" ::: "memory");
    else if (g == 62)  asm volatile("s_waitcnt vmcnt(0)" ::: "memory");
    __builtin_amdgcn_s_barrier();
  }

  const int rq = fg * 4, cn = fr;
  if (mode == 0){
    short* o = (short*)outp;
    #pragma unroll
    for (int mi = 0; mi < 8; ++mi)
      #pragma unroll
      for (int ni = 0; ni < 4; ++ni)
        #pragma unroll
        for (int i = 0; i < 4; ++i){
          int mrow = bm*256 + wr*128 + mi*16 + rq + i;
          int ncol = bn*256 + wc*64 + ni*16 + cn;
          int b = mrow >> 12, s = mrow & 4095, h = ncol >> 7, dd = ncol & 127;
          o[((size_t)(b*16 + h)*4096 + s)*128 + dd] = f2bf(acc[mi][ni][i]);
        }
  } else {
    float* o = (float*)outp;
    #pragma unroll
    for (int mi = 0; mi < 8; ++mi)
      #pragma unroll
      for (int ni = 0; ni < 4; ++ni)
        #pragma unroll
        for (int i = 0; i < 4; ++i){
          int mrow = bm*256 + wr*128 + mi*16 + rq + i;
          int ncol = bn*256 + wc*64 + ni*16 + cn;
          o[(size_t)mrow*2048 + ncol] = acc[mi][ni][i];
        }
  }
  #undef BUFB
  #undef STGA
  #undef STGB
}

// ---------------------------------------------------------------------------
// qsum pass: partial[bh*16+sl][d] = sum over 256 rows of q (vectorized).
__global__ __launch_bounds__(256) void k_qsum(const short* __restrict__ qb,
                                              float* __restrict__ partial){
  const int bid = blockIdx.x, bh = bid >> 4, sl = bid & 15;
  const int t = threadIdx.x, dvec = t & 15, rg = t >> 4;
  const short* qp = qb + (size_t)bh*4096*128 + (size_t)sl*256*128;
  float acc[8];
  #pragma unroll
  for (int e = 0; e < 8; ++e) acc[e] = 0.f;
  for (int r = 0; r < 16; ++r){
    s16x8 v = *(const s16x8*)(qp + (rg*16 + r)*128 + dvec*8);
    #pragma unroll
    for (int e = 0; e < 8; ++e) acc[e] += bf2f(v[e]);
  }
  __shared__ float red[16][128];
  #pragma unroll
  for (int e = 0; e < 8; ++e) red[rg][dvec*8 + e] = acc[e];
  __syncthreads();
  if (t < 128){
    float s = 0.f;
    #pragma unroll
    for (int r = 0; r < 16; ++r) s += red[r][t];
    partial[(size_t)bid*128 + t] = s;
  }
}

// rel + softmax over memories from qsum partials. One block per (b,h).
__global__ __launch_bounds__(128) void k_relw(const float* __restrict__ partial,
                                              const float* __restrict__ lm,
                                              const float* __restrict__ kc,
                                              float* __restrict__ wsm){
  const int bh = blockIdx.x, b = bh >> 4, h = bh & 15, t = threadIdx.x;
  __shared__ float tmp[128];
  __shared__ float relv[4];
  float qs = 0.f;
  #pragma unroll
  for (int sl = 0; sl < 16; ++sl) qs += partial[((size_t)bh*16 + sl)*128 + t];
  for (int m = 0; m < 4; ++m){
    tmp[t] = qs * lm[(m*16 + h)*128 + t];
    __syncthreads();
    for (int o = 64; o > 0; o >>= 1){ if (t < o) tmp[t] += tmp[t+o]; __syncthreads(); }
    if (t == 0) relv[m] = tmp[0] * (1.f/4096.f);
    __syncthreads();
  }
  if (t == 0){
    float w[4]; float mx = -1e30f;
    for (int m = 0; m < 4; ++m){
      float s = 0.f;
      for (int hh = 0; hh < 16; ++hh) s += kc[m*16 + hh];
      w[m] = (s >= 1e-6f) ? relv[m] : -1e30f;
      mx = fmaxf(mx, w[m]);
    }
    float den = 0.f;
    for (int m = 0; m < 4; ++m){ w[m] = __expf(w[m] - mx); den += w[m]; }
    for (int m = 0; m < 4; ++m) wsm[(m*2 + b)*16 + h] = w[m] / den;
  }
}

// ---------------------------------------------------------------------------
// Pass A: per-chunk Sc^T[e][d] = sum_k v[k][e]*sk[k][d] (bf16) and zc[d].
// LDS tiles swizzled (col ^= (row&7)<<3).
__global__ __launch_bounds__(256) void k_passA(const short* __restrict__ kin,
                                               const short* __restrict__ vin,
                                               short* __restrict__ Sc,
                                               float* __restrict__ zc){
  __shared__ short skT[16384];
  __shared__ short vT[16384];
  const int bid = blockIdx.x;                 // bh*32 + c
  const int tid = threadIdx.x, lane = tid & 63, wv = tid >> 6;
  const int wm = wv >> 1, wn = wv & 1;
  const size_t rb = (size_t)bid * 16384;
  const short* kp = kin + rb;
  const short* vp = vin + rb;
  const int kl = tid >> 1, dh = (tid & 1) * 64;
  #pragma unroll
  for (int j = 0; j < 8; ++j){
    s16x8 pk = *(const s16x8*)(kp + kl*128 + dh + j*8);
    s16x8 pv = *(const s16x8*)(vp + kl*128 + dh + j*8);
    #pragma unroll
    for (int e = 0; e < 8; ++e){
      int dd = dh + j*8 + e;
      int pc = kl ^ ((dd & 7) << 3);
      skT[dd*128 + pc] = f2bf(seplus(bf2f(pk[e])));
      vT [dd*128 + pc] = pv[e];
    }
  }
  __syncthreads();
  {
    const int row = tid >> 1, half = tid & 1;
    const int sx = (row & 7) << 3;
    float z = 0.f;
    #pragma unroll
    for (int j = 0; j < 8; ++j){
      int cg = half*64 + j*8;
      s16x8 v = *(const s16x8*)(skT + row*128 + (cg ^ sx));
      #pragma unroll
      for (int e = 0; e < 8; ++e) z += bf2f(v[e]);
    }
    z += __shfl_xor(z, 1);
    if (half == 0) zc[(size_t)bid*128 + row] = z;
  }
  f32x4 acc[4][4]; ZERO44(acc);
  mm_tile_swz<128,4>(vT, skT, acc, lane, wm, wn);
  short* o = Sc + rb;
  const int rq = (lane >> 4) * 4, cn = lane & 15;
  #pragma unroll
  for (int mi = 0; mi < 4; ++mi)
    #pragma unroll
    for (int ni = 0; ni < 4; ++ni)
      #pragma unroll
      for (int i = 0; i < 4; ++i){
        int e = wm*64 + mi*16 + rq + i, d = wn*64 + ni*16 + cn;
        o[e*128 + d] = f2bf(acc[mi][ni][i]);
      }
}

// Pass B (parallel): exclusive prefix over 32 chunks, one thread per element.
__global__ __launch_bounds__(256) void k_scanS(short* __restrict__ S){
  const int gid = blockIdx.x*256 + threadIdx.x;       // < 524288
  const int bh = gid >> 14, elem = gid & 16383;
  short* p = S + (size_t)bh*32*16384 + elem;
  float a[32];
  #pragma unroll
  for (int c = 0; c < 32; ++c) a[c] = bf2f(p[(size_t)c*16384]);
  float run = 0.f;
  #pragma unroll
  for (int c = 0; c < 32; ++c){ float cur = a[c]; p[(size_t)c*16384] = f2bf(run); run += cur; }
}

__global__ __launch_bounds__(256) void k_scanZ(float* __restrict__ z){
  const int gid = blockIdx.x*256 + threadIdx.x;       // < 4096
  const int bh = gid >> 7, d = gid & 127;
  float* p = z + (size_t)bh*32*128 + d;
  float a[32];
  #pragma unroll
  for (int c = 0; c < 32; ++c) a[c] = p[c*128];
  float run = 0.f;
  #pragma unroll
  for (int c = 0; c < 32; ++c){ float cur = a[c]; p[c*128] = run; run += cur; }
}

// ---------------------------------------------------------------------------
// Pass M: memory retrieval, writes g*sum_m w_m*(sq@mem_m)/max(norm_m,eps).
__global__ __launch_bounds__(256) void k_passM(const short* __restrict__ qb,
    const short* __restrict__ memT, const float* __restrict__ mn,
    const float* __restrict__ wsm, const float* __restrict__ gate,
    short* __restrict__ memout){
  __shared__ short X[16384];
  __shared__ short Y[16384];
  __shared__ float NM[128];
  const int bid = blockIdx.x, bh = bid >> 5, b = bh >> 4, h = bh & 15;
  const int tid = threadIdx.x, lane = tid & 63, wv = tid >> 6;
  const int wm = wv >> 1, wn = wv & 1;
  const int rq = (lane >> 4) * 4, cn = lane & 15;
  const size_t rb = (size_t)bid * 16384;
  const short* qp = qb + rb;
  for (int i = tid; i < 2048; i += 256){
    s16x8 v = *(const s16x8*)(qp + i*8);
    s16x8 o;
    #pragma unroll
    for (int e = 0; e < 8; ++e) o[e] = f2bf(seplus(bf2f(v[e])));
    int row = i >> 4, cg = (i & 15) << 3;
    *(s16x8*)(X + row*128 + (cg ^ ((row & 7) << 3))) = o;
  }
  f32x4 macc[4][4]; ZERO44(macc);
  for (int m = 0; m < 4; ++m){
    __syncthreads();   // X ready (m=0); Y/NM reads of prior iter done
    const short* mt = memT + (size_t)(m*16 + h)*16384;
    for (int i = tid; i < 2048; i += 256){
      int row = i >> 4, cg = (i & 15) << 3;
      *(s16x8*)(Y + row*128 + (cg ^ ((row & 7) << 3))) = *(const s16x8*)(mt + i*8);
    }
    {
      const int row = tid >> 1, half = tid & 1;
      const int sx = (row & 7) << 3;
      const float* mnp = mn + (m*16 + h)*128;
      float s = 0.f;
      #pragma unroll
      for (int j = 0; j < 8; ++j){
        int cg = half*64 + j*8;
        s16x8 v = *(const s16x8*)(X + row*128 + (cg ^ sx));
        #pragma unroll
        for (int e = 0; e < 8; ++e) s += bf2f(v[e]) * mnp[cg + e];
      }
      s += __shfl_xor(s, 1);
      if (half == 0) NM[row] = s;
    }
    __syncthreads();
    f32x4 am[4][4]; ZERO44(am);
    mm_tile_swz<128,4>(X, Y, am, lane, wm, wn);
    const float wmv = wsm[(m*2 + b)*16 + h];
    #pragma unroll
    for (int mi = 0; mi < 4; ++mi)
      #pragma unroll
      for (int i = 0; i < 4; ++i){
        int q = wm*64 + mi*16 + rq + i;
        float f = wmv / fmaxf(NM[q], 1e-6f);
        #pragma unroll
        for (int ni = 0; ni < 4; ++ni) macc[mi][ni][i] += f * am[mi][ni][i];
      }
  }
  const float g = 1.f / (1.f + __expf(-gate[h]));
  short* op = memout + rb;
  #pragma unroll
  for (int mi = 0; mi < 4; ++mi)
    #pragma unroll
    for (int ni = 0; ni < 4; ++ni)
      #pragma unroll
      for (int i = 0; i < 4; ++i){
        int q = wm*64 + mi*16 + rq + i, e = wn*64 + ni*16 + cn;
        op[q*128 + e] = f2bf(g * macc[mi][ni][i]);
      }
}

// ---------------------------------------------------------------------------
// Pass C: local attention per (bh,chunk) + gate-combine with memout.
__global__ __launch_bounds__(256) void k_passC(const short* __restrict__ qb,
    const short* __restrict__ kin, const short* __restrict__ vin,
    const short* __restrict__ Spref, const float* __restrict__ zpref,
    const short* __restrict__ memout, const float* __restrict__ gate,
    short* __restrict__ combined){
  __shared__ short X[16384];   // sq -> masked scores   (swizzled)
  __shared__ short Y[16384];   // sk -> Spref^T -> v^T  (swizzled)
  __shared__ float NL[128];
  const int bid = blockIdx.x, bh = bid >> 5, c = bid & 31, b = bh >> 4, h = bh & 15;
  const int tid = threadIdx.x, lane = tid & 63, wv = tid >> 6;
  const int wm = wv >> 1, wn = wv & 1;
  const int rq = (lane >> 4) * 4, cn = lane & 15;
  const size_t rb = (size_t)bid * 16384;
  const short* qp = qb + rb;
  const short* kp = kin + rb;
  const short* vp = vin + rb;

  for (int i = tid; i < 2048; i += 256){
    s16x8 a = *(const s16x8*)(qp + i*8);
    s16x8 bb = *(const s16x8*)(kp + i*8);
    s16x8 oa, ob;
    #pragma unroll
    for (int e = 0; e < 8; ++e){ oa[e] = f2bf(seplus(bf2f(a[e]))); ob[e] = f2bf(seplus(bf2f(bb[e]))); }
    int row = i >> 4, cg = (i & 15) << 3;
    int po = row*128 + (cg ^ ((row & 7) << 3));
    *(s16x8*)(X + po) = oa;
    *(s16x8*)(Y + po) = ob;
  }
  __syncthreads();

  f32x4 sc[4][4]; ZERO44(sc);
  mm_tile_swz<128,4>(X, Y, sc, lane, wm, wn);    // scores[q][k]
  __syncthreads();

  for (int i = tid; i < 2048; i += 256){
    int row = i >> 4, cg = (i & 15) << 3;
    *(s16x8*)(Y + row*128 + (cg ^ ((row & 7) << 3))) = *(const s16x8*)(Spref + rb + i*8);
  }
  {
    const int row = tid >> 1, half = tid & 1;
    const int sx = (row & 7) << 3;
    const float* zp = zpref + (size_t)bid*128;
    float s = 0.f;
    #pragma unroll
    for (int j = 0; j < 8; ++j){
      int cg = half*64 + j*8;
      s16x8 v = *(const s16x8*)(X + row*128 + (cg ^ sx));
      #pragma unroll
      for (int e = 0; e < 8; ++e) s += bf2f(v[e]) * zp[cg + e];
    }
    s += __shfl_xor(s, 1);
    if (half == 0) NL[row] = s;
  }
  __syncthreads();

  f32x4 oacc[4][4]; ZERO44(oacc);
  mm_tile_swz<128,4>(X, Y, oacc, lane, wm, wn);  // out1[q][e] = sq @ Spref
  __syncthreads();

  // X <- masked scores (bf16, swizzled scalar writes), Y <- v^T (swizzled)
  #pragma unroll
  for (int mi = 0; mi < 4; ++mi)
    #pragma unroll
    for (int ni = 0; ni < 4; ++ni)
      #pragma unroll
      for (int i = 0; i < 4; ++i){
        int q = wm*64 + mi*16 + rq + i, k2 = wn*64 + ni*16 + cn;
        X[q*128 + (k2 ^ ((q & 7) << 3))] = f2bf((k2 <= q) ? sc[mi][ni][i] : 0.f);
      }
  const int klv = tid >> 1, dh = (tid & 1) * 64;
  #pragma unroll
  for (int j = 0; j < 8; ++j){
    s16x8 pv = *(const s16x8*)(vp + klv*128 + dh + j*8);
    #pragma unroll
    for (int e = 0; e < 8; ++e){
      int dd = dh + j*8 + e;
      Y[dd*128 + (klv ^ ((dd & 7) << 3))] = pv[e];
    }
  }
  __syncthreads();
  {
    const int row = tid >> 1, half = tid & 1;
    const int sx = (row & 7) << 3;
    float s = 0.f;
    #pragma unroll
    for (int j = 0; j < 8; ++j){
      int cg = half*64 + j*8;
      s16x8 v = *(const s16x8*)(X + row*128 + (cg ^ sx));
      #pragma unroll
      for (int e = 0; e < 8; ++e) s += bf2f(v[e]);
    }
    s += __shfl_xor(s, 1);
    if (half == 0) NL[row] += s;
  }
  __syncthreads();

  mm_tile_swz<128,4>(X, Y, oacc, lane, wm, wn);  // + scoresM @ v

  const float g = 1.f / (1.f + __expf(-gate[h]));
  const float og = 1.f - g;
  const short* mo = memout + rb;
  #pragma unroll
  for (int mi = 0; mi < 4; ++mi)
    #pragma unroll
    for (int ni = 0; ni < 4; ++ni)
      #pragma unroll
      for (int i = 0; i < 4; ++i){
        int q = wm*64 + mi*16 + rq + i, e = wn*64 + ni*16 + cn;
        float nl = fmaxf(NL[q], 1e-6f);
        float outv = bf2f(mo[q*128 + e]) + og * (oacc[mi][ni][i] / nl);
        combined[((size_t)b*4096 + c*128 + q)*2048 + h*128 + e] = f2bf(outv);
      }
}

// ---------------------------------------------------------------------------
extern "C" void kernel_launch(void* const* d_in, const int* in_sizes, int n_in,
                              void* d_out, int out_size, void* d_ws, size_t ws_size,
                              hipStream_t stream){
  const float* hs   = (const float*)d_in[0];
  const float* wq   = (const float*)d_in[1];
  const float* wk   = (const float*)d_in[2];
  const float* wvp  = (const float*)d_in[3];
  const float* wo   = (const float*)d_in[4];
  const float* gate = (const float*)d_in[5];
  const float* mem  = (const float*)d_in[6];
  const float* mn   = (const float*)d_in[7];
  const float* lm   = (const float*)d_in[8];
  const float* kc   = (const float*)d_in[9];

  char* base = (char*)d_ws; size_t off = 0;
  auto alloc = [&](size_t bytes)->void*{
    void* r = base + off; off = (off + bytes + 255) & ~(size_t)255; return r;
  };
  short* hs_b  = (short*)alloc(16777216ull*2);   // reused as memout after proj
  short* wq_b  = (short*)alloc(4194304ull*2);
  short* wk_b  = (short*)alloc(4194304ull*2);
  short* wv_b  = (short*)alloc(4194304ull*2);
  short* wo_b  = (short*)alloc(4194304ull*2);
  short* q_b   = (short*)alloc(16777216ull*2);
  short* k_b   = (short*)alloc(16777216ull*2);
  short* v_b   = (short*)alloc(16777216ull*2);
  short* memT  = (short*)alloc(1048576ull*2);
  float* wsm   = (float*)alloc(128*4);
  short* SZ    = (short*)alloc(16777216ull*2);   // Sc -> Spref (in place)
  float* zz    = (float*)alloc(131072ull*4);     // zc -> zpref (in place)
  short* comb  = (short*)alloc(16777216ull*2);
  float* qpart = (float*)alloc(512ull*128*4);
  short* memout = hs_b;  // alias: hs_b dead after proj GEMMs

  k_f2b4<<<4096, 256, 0, stream>>>(hs,  hs_b, 4194304);
  k_f2b4<<<1024, 256, 0, stream>>>(wq,  wq_b, 1048576);
  k_f2b4<<<1024, 256, 0, stream>>>(wk,  wk_b, 1048576);
  k_f2b4<<<1024, 256, 0, stream>>>(wvp, wv_b, 1048576);
  k_f2b4<<<1024, 256, 0, stream>>>(wo,  wo_b, 1048576);
  k_memT<<<64, 256, 0, stream>>>(mem, memT);

  k_gemm2<<<256, 512, 0, stream>>>(hs_b, wq_b, q_b, 0);
  k_gemm2<<<256, 512, 0, stream>>>(hs_b, wk_b, k_b, 0);
  k_gemm2<<<256, 512, 0, stream>>>(hs_b, wv_b, v_b, 0);

  k_qsum<<<512, 256, 0, stream>>>(q_b, qpart);
  k_relw<<<32, 128, 0, stream>>>(qpart, lm, kc, wsm);
  k_passA<<<1024, 256, 0, stream>>>(k_b, v_b, SZ, zz);
  k_scanS<<<2048, 256, 0, stream>>>(SZ);
  k_scanZ<<<16, 256, 0, stream>>>(zz);
  k_passM<<<1024, 256, 0, stream>>>(q_b, memT, mn, wsm, gate, memout);
  k_passC<<<1024, 256, 0, stream>>>(q_b, k_b, v_b, SZ, zz, memout, gate, comb);

  k_gemm2<<<256, 512, 0, stream>>>(comb, wo_b, d_out, 1);
}